// Round 6
// baseline (682.590 us; speedup 1.0000x reference)
//
#include <hip/hip_runtime.h>
#include <hip/hip_bf16.h>

// Problem constants (fixed by the reference setup)
#define NN   50000
#define EE   800000
#define FIN  128
#define CC   64
#define HH   4
#define GG   512
#define CAP  64          // per-node CSR capacity (Poisson(16) in-degree; P(>64) ~ 2e-18)

__device__ __forceinline__ float leaky02(float x) { return x >= 0.f ? x : 0.2f * x; }
__device__ __forceinline__ float leaky01(float x) { return x >= 0.f ? x : 0.01f * x; }

// ---------------------------------------------------------------------------
// CSR build: histogram placement with fixed capacity. Self-loops NOT stored
// (handled implicitly in aggregation). Harness stages integer inputs as int32.
// ---------------------------------------------------------------------------
__global__ __launch_bounds__(256) void build_csr(const int* __restrict__ ei,
                                                 int* __restrict__ deg,
                                                 int* __restrict__ csr) {
    int e = blockIdx.x * 256 + threadIdx.x;
    if (e >= EE) return;
    int s = ei[e];         // edge_index[0][e]
    int d = ei[EE + e];    // edge_index[1][e]
    if ((unsigned)d >= NN || (unsigned)s >= NN) return;  // defensive
    int pos = atomicAdd(&deg[d], 1);
    if (pos < CAP) csr[d * CAP + pos] = s;
}

// ---------------------------------------------------------------------------
// Register-tiled GEMM: h = x @ W, x:[NN,K], W:[K,256], tile 128x128, BK=32.
// 256 threads, each owns 8x8 accs. Fused al_s/al_d epilogue.
// ---------------------------------------------------------------------------
template <int K>
__global__ __launch_bounds__(256, 3) void gemm_gat(const float* __restrict__ x,
                                                   const float* __restrict__ W,
                                                   const float* __restrict__ a_src,
                                                   const float* __restrict__ a_dst,
                                                   float* __restrict__ h_out,
                                                   float* __restrict__ al_s,
                                                   float* __restrict__ al_d) {
    __shared__ float Xs[32 * 128];   // [k][slot*8 + m&7], swizzled
    __shared__ float Ws[32 * 128];   // [k][n] linear
    const int t  = threadIdx.x;
    const int tc = t & 15;           // col group (8 cols each)
    const int tr = t >> 4;           // row group (8 rows each)
    const int r0 = blockIdx.x * 128;
    const int c0 = blockIdx.y * 128;

    float acc[8][8];
#pragma unroll
    for (int i = 0; i < 8; ++i)
#pragma unroll
        for (int j = 0; j < 8; ++j) acc[i][j] = 0.f;

    for (int k0 = 0; k0 < K; k0 += 32) {
        // ---- stage X tile: 128 rows x 32 k, store transposed+swizzled ----
#pragma unroll
        for (int jj = 0; jj < 4; ++jj) {
            int id = t + jj * 256;           // 0..1023
            int m  = id >> 3;                // 0..127
            int k4 = id & 7;                 // float4 index along k
            int row = r0 + m;
            row = row < NN ? row : NN - 1;   // clamp (stores are guarded later)
            float4 v = *(const float4*)(x + (size_t)row * K + k0 + k4 * 4);
#pragma unroll
            for (int c = 0; c < 4; ++c) {
                int k = k4 * 4 + c;
                int slot = (m >> 3) ^ (k >> 2);
                Xs[k * 128 + slot * 8 + (m & 7)] = ((const float*)&v)[c];
            }
        }
        // ---- stage W tile: 32 k x 128 n, linear ----
#pragma unroll
        for (int jj = 0; jj < 4; ++jj) {
            int id = t + jj * 256;
            int k  = id >> 5;                // 0..31
            int n4 = id & 31;                // 0..31
            float4 v = *(const float4*)(W + (size_t)(k0 + k) * 256 + c0 + n4 * 4);
            *(float4*)(Ws + k * 128 + n4 * 4) = v;
        }
        __syncthreads();

#pragma unroll
        for (int k = 0; k < 32; ++k) {
            int aslot = tr ^ (k >> 2);
            const float* ax = &Xs[k * 128 + aslot * 8];
            const float* bw = &Ws[k * 128 + tc * 8];
            float a0[8], b0[8];
            *(float4*)&a0[0] = *(const float4*)&ax[0];
            *(float4*)&a0[4] = *(const float4*)&ax[4];
            *(float4*)&b0[0] = *(const float4*)&bw[0];
            *(float4*)&b0[4] = *(const float4*)&bw[4];
#pragma unroll
            for (int i = 0; i < 8; ++i)
#pragma unroll
                for (int j = 0; j < 8; ++j)
                    acc[i][j] = fmaf(a0[i], b0[j], acc[i][j]);
        }
        __syncthreads();
    }

    // ---- epilogue: write h, fused al_s/al_d ----
    const int colbase = c0 + tc * 8;
    const int head = colbase >> 6;   // 8 cols never straddle a head boundary
    float as_c[8], ad_c[8];
#pragma unroll
    for (int j = 0; j < 8; ++j) {
        as_c[j] = a_src[colbase + j];
        ad_c[j] = a_dst[colbase + j];
    }
#pragma unroll
    for (int i = 0; i < 8; ++i) {
        int row = r0 + tr * 8 + i;
        bool ok = row < NN;
        if (ok) {
            *(float4*)(h_out + (size_t)row * 256 + colbase)     = *(float4*)&acc[i][0];
            *(float4*)(h_out + (size_t)row * 256 + colbase + 4) = *(float4*)&acc[i][4];
        }
        float ps = 0.f, pd = 0.f;
#pragma unroll
        for (int j = 0; j < 8; ++j) {
            ps = fmaf(acc[i][j], as_c[j], ps);
            pd = fmaf(acc[i][j], ad_c[j], pd);
        }
#pragma unroll
        for (int off = 1; off <= 4; off <<= 1) {
            ps += __shfl_xor(ps, off, 64);
            pd += __shfl_xor(pd, off, 64);
        }
        if (ok && (tc & 7) == 0) {
            al_s[(size_t)row * 4 + head] = ps;
            al_d[(size_t)row * 4 + head] = pd;
        }
    }
}

// ---------------------------------------------------------------------------
// Per-dst segment softmax + aggregation. One wave per dst node.
// Lane j owns edge j (d<=64): computes alpha/e/coef ONCE, coef -> LDS.
// Channel remap: lane L owns flat channels 4L..4L+3 (head L>>4): gather is one
// dwordx4/lane/edge. Edge loop unrolled 8/4/1 with hoisted loads for MLP.
// ---------------------------------------------------------------------------
__global__ __launch_bounds__(256) void gat_aggregate(const float* __restrict__ h_buf,
                                                     const float* __restrict__ al_s,
                                                     const float* __restrict__ al_d,
                                                     const int* __restrict__ deg,
                                                     const int* __restrict__ csr,
                                                     const float* __restrict__ bias,
                                                     float* __restrict__ xout) {
    __shared__ __align__(16) float els[4][64][4];   // [wave][edge][head] coef
    const int w    = threadIdx.x >> 6;
    const int lane = threadIdx.x & 63;
    const int n    = blockIdx.x * 4 + w;
    if (n >= NN) return;                 // grid is exact: never taken
    const int d = min(deg[n], CAP);

    float4 ad4 = *(const float4*)(al_d + (size_t)n * 4);
    float4 as4 = *(const float4*)(al_s + (size_t)n * 4);
    const float* adp = (const float*)&ad4;
    const float* asp = (const float*)&as4;

    float aself[4];
#pragma unroll
    for (int h = 0; h < 4; ++h) aself[h] = leaky02(asp[h] + adp[h]);

    // ---- lane j loads its edge and computes alpha ----
    int s_lane = 0;
    float a_lane[4];
    if (lane < d) {
        s_lane = csr[(size_t)n * CAP + lane];
        float4 s4 = *(const float4*)(al_s + (size_t)s_lane * 4);
        const float* sp = (const float*)&s4;
#pragma unroll
        for (int h = 0; h < 4; ++h) a_lane[h] = leaky02(sp[h] + adp[h]);
    } else {
#pragma unroll
        for (int h = 0; h < 4; ++h) a_lane[h] = -INFINITY;
    }

    // ---- max over edges + self ----
    float mx[4];
#pragma unroll
    for (int h = 0; h < 4; ++h) {
        mx[h] = fmaxf(aself[h], a_lane[h]);
#pragma unroll
        for (int off = 32; off; off >>= 1) mx[h] = fmaxf(mx[h], __shfl_xor(mx[h], off, 64));
    }

    // ---- e per edge (once), sum via tree, coef -> LDS ----
    float e[4], sm[4];
#pragma unroll
    for (int h = 0; h < 4; ++h) {
        e[h] = (lane < d) ? expf(a_lane[h] - mx[h]) : 0.f;
        sm[h] = e[h];
#pragma unroll
        for (int off = 32; off; off >>= 1) sm[h] += __shfl_xor(sm[h], off, 64);
    }
    float eself[4], inv[4];
    float4 coef;
    float* cf = (float*)&coef;
#pragma unroll
    for (int h = 0; h < 4; ++h) {
        eself[h] = expf(aself[h] - mx[h]);
        inv[h] = 1.f / (sm[h] + eself[h] + 1e-16f);
        cf[h] = e[h] * inv[h];
    }
    *(float4*)&els[w][lane][0] = coef;

    // ---- pass 3: lane owns flat channels 4L..4L+3 (head hh) ----
    const int hh = lane >> 4;
    const float* __restrict__ hb = h_buf + (size_t)lane * 4;
    const float selfc = eself[hh] * inv[hh];
    float4 hv = *(const float4*)(hb + (size_t)n * 256);
    float acc0 = hv.x * selfc, acc1 = hv.y * selfc, acc2 = hv.z * selfc, acc3 = hv.w * selfc;

    int j = 0;
    for (; j + 7 < d; j += 8) {
        int ss[8];
#pragma unroll
        for (int q = 0; q < 8; ++q) ss[q] = __shfl(s_lane, j + q, 64);
        float4 hq[8];
#pragma unroll
        for (int q = 0; q < 8; ++q) hq[q] = *(const float4*)(hb + (size_t)ss[q] * 256);
        float cq[8];
#pragma unroll
        for (int q = 0; q < 8; ++q) cq[q] = els[w][j + q][hh];
#pragma unroll
        for (int q = 0; q < 8; ++q) {
            acc0 = fmaf(hq[q].x, cq[q], acc0);
            acc1 = fmaf(hq[q].y, cq[q], acc1);
            acc2 = fmaf(hq[q].z, cq[q], acc2);
            acc3 = fmaf(hq[q].w, cq[q], acc3);
        }
    }
    for (; j + 3 < d; j += 4) {
        int ss[4];
#pragma unroll
        for (int q = 0; q < 4; ++q) ss[q] = __shfl(s_lane, j + q, 64);
        float4 hq[4];
#pragma unroll
        for (int q = 0; q < 4; ++q) hq[q] = *(const float4*)(hb + (size_t)ss[q] * 256);
        float cq[4];
#pragma unroll
        for (int q = 0; q < 4; ++q) cq[q] = els[w][j + q][hh];
#pragma unroll
        for (int q = 0; q < 4; ++q) {
            acc0 = fmaf(hq[q].x, cq[q], acc0);
            acc1 = fmaf(hq[q].y, cq[q], acc1);
            acc2 = fmaf(hq[q].z, cq[q], acc2);
            acc3 = fmaf(hq[q].w, cq[q], acc3);
        }
    }
    for (; j < d; ++j) {
        int s = __shfl(s_lane, j, 64);
        float cj = els[w][j][hh];
        float4 hj = *(const float4*)(hb + (size_t)s * 256);
        acc0 = fmaf(hj.x, cj, acc0);
        acc1 = fmaf(hj.y, cj, acc1);
        acc2 = fmaf(hj.z, cj, acc2);
        acc3 = fmaf(hj.w, cj, acc3);
    }

    // ---- head mean: lanes {L, L^16, L^32, L^48} hold same within-head chans
#pragma unroll
    for (int off = 16; off <= 32; off <<= 1) {
        acc0 += __shfl_xor(acc0, off, 64);
        acc1 += __shfl_xor(acc1, off, 64);
        acc2 += __shfl_xor(acc2, off, 64);
        acc3 += __shfl_xor(acc3, off, 64);
    }
    if (lane < 16) {
        float4 o;
        o.x = leaky01(acc0 * 0.25f + bias[lane * 4 + 0]);
        o.y = leaky01(acc1 * 0.25f + bias[lane * 4 + 1]);
        o.z = leaky01(acc2 * 0.25f + bias[lane * 4 + 2]);
        o.w = leaky01(acc3 * 0.25f + bias[lane * 4 + 3]);
        *(float4*)(xout + (size_t)n * 64 + lane * 4) = o;
    }
}

// ---------------------------------------------------------------------------
// Readout: one block per graph g; batch_index is sorted -> binary search.
// ---------------------------------------------------------------------------
__global__ __launch_bounds__(256) void readout(const float* __restrict__ x,
                                               const int* __restrict__ batch,
                                               float* __restrict__ gmp,
                                               float* __restrict__ gap) {
    int g = blockIdx.x;
    int a = 0, b = NN;
    while (a < b) { int m = (a + b) >> 1; if (batch[m] < g) a = m + 1; else b = m; }
    int lo = a;
    a = lo; b = NN;
    while (a < b) { int m = (a + b) >> 1; if (batch[m] < g + 1) a = m + 1; else b = m; }
    int hi = a;

    int t = threadIdx.x, c = t & 63, s = t >> 6;
    float mx = -INFINITY, sm = 0.f;
    for (int n = lo + s; n < hi; n += 4) {
        float v = x[(size_t)n * 64 + c];
        mx = fmaxf(mx, v);
        sm += v;
    }
    __shared__ float smx[256], ssm[256];
    smx[t] = mx; ssm[t] = sm;
    __syncthreads();
    if (t < 64) {
        mx = fmaxf(fmaxf(smx[t], smx[t + 64]), fmaxf(smx[t + 128], smx[t + 192]));
        sm = ssm[t] + ssm[t + 64] + ssm[t + 128] + ssm[t + 192];
        int cnt = hi - lo;
        gmp[g * 64 + t] = mx;
        gap[g * 64 + t] = sm / fmaxf((float)cnt, 1.0f);
    }
}

// ---------------------------------------------------------------------------
// Final MLP: one wave per graph.
// ---------------------------------------------------------------------------
__global__ __launch_bounds__(64) void mlp_readout(const float* __restrict__ gmp,
                                                  const float* __restrict__ gap,
                                                  const float* __restrict__ Wr1,
                                                  const float* __restrict__ br1,
                                                  const float* __restrict__ Wr2,
                                                  const float* __restrict__ br2,
                                                  float* __restrict__ out) {
    int g = blockIdx.x;
    int j = threadIdx.x;  // 0..63
    double acc = (double)br1[j];
    for (int i = 0; i < 64; ++i) acc += (double)gmp[g * 64 + i] * (double)Wr1[i * 64 + j];
    for (int i = 0; i < 64; ++i) acc += (double)gap[g * 64 + i] * (double)Wr1[(64 + i) * 64 + j];
    float v = (float)acc;
    v = v >= 0.f ? v : 0.01f * v;
    double tv = (double)v * (double)Wr2[j];
#pragma unroll
    for (int off = 32; off; off >>= 1) tv += __shfl_xor(tv, off, 64);
    if (j == 0) out[g] = (float)(tv + (double)br2[0]);
}

// ---------------------------------------------------------------------------
extern "C" void kernel_launch(void* const* d_in, const int* in_sizes, int n_in,
                              void* d_out, int out_size, void* d_ws, size_t ws_size,
                              hipStream_t stream) {
    const float* x   = (const float*)d_in[0];
    const int* ei    = (const int*)d_in[1];    // int inputs staged as int32
    // d_in[2] edge_attr unused
    const int* batch = (const int*)d_in[3];
    const float* W0  = (const float*)d_in[4];
    const float* as0 = (const float*)d_in[5];
    const float* ad0 = (const float*)d_in[6];
    const float* b0  = (const float*)d_in[7];
    const float* W1  = (const float*)d_in[8];
    const float* as1 = (const float*)d_in[9];
    const float* ad1 = (const float*)d_in[10];
    const float* b1  = (const float*)d_in[11];
    const float* W2  = (const float*)d_in[12];
    const float* as2 = (const float*)d_in[13];
    const float* ad2 = (const float*)d_in[14];
    const float* b2  = (const float*)d_in[15];
    const float* Wr1 = (const float*)d_in[16];
    const float* br1 = (const float*)d_in[17];
    const float* Wr2 = (const float*)d_in[18];
    const float* br2 = (const float*)d_in[19];
    float* out = (float*)d_out;

    // workspace layout
    float* h_buf = (float*)d_ws;                 // NN*256
    float* al_s  = h_buf + (size_t)NN * 256;     // NN*4
    float* al_d  = al_s + (size_t)NN * 4;        // NN*4
    float* xbuf  = al_d + (size_t)NN * 4;        // NN*64
    float* gmp   = xbuf + (size_t)NN * 64;       // GG*64
    float* gap   = gmp + (size_t)GG * 64;        // GG*64
    int*   deg   = (int*)(gap + (size_t)GG * 64);// NN
    int*   csr   = deg + NN;                     // NN*CAP

    hipMemsetAsync(deg, 0, NN * sizeof(int), stream);
    build_csr<<<(EE + 255) / 256, 256, 0, stream>>>(ei, deg, csr);

    const dim3 gemm_grid((NN + 127) / 128, 2);
    const int agg_grid = (NN + 3) / 4;

    // layer 0
    gemm_gat<FIN><<<gemm_grid, 256, 0, stream>>>(x, W0, as0, ad0, h_buf, al_s, al_d);
    gat_aggregate<<<agg_grid, 256, 0, stream>>>(h_buf, al_s, al_d, deg, csr, b0, xbuf);
    // layer 1
    gemm_gat<CC><<<gemm_grid, 256, 0, stream>>>(xbuf, W1, as1, ad1, h_buf, al_s, al_d);
    gat_aggregate<<<agg_grid, 256, 0, stream>>>(h_buf, al_s, al_d, deg, csr, b1, xbuf);
    // layer 2
    gemm_gat<CC><<<gemm_grid, 256, 0, stream>>>(xbuf, W2, as2, ad2, h_buf, al_s, al_d);
    gat_aggregate<<<agg_grid, 256, 0, stream>>>(h_buf, al_s, al_d, deg, csr, b2, xbuf);

    // readout
    readout<<<GG, 256, 0, stream>>>(xbuf, batch, gmp, gap);
    mlp_readout<<<GG, 64, 0, stream>>>(gmp, gap, Wr1, br1, Wr2, br2, out);
}

// Round 9
// 529.916 us; speedup vs baseline: 1.2881x; 1.2881x over previous
//
#include <hip/hip_runtime.h>
#include <hip/hip_bf16.h>
#include <hip/hip_fp16.h>

// Problem constants (fixed by the reference setup)
#define NN   50000
#define EE   800000
#define FIN  128
#define CC   64
#define HH   4
#define GG   512
#define CAP  64          // per-node CSR capacity (Poisson(16) in-degree; P(>64) ~ 2e-18)

__device__ __forceinline__ float leaky02(float x) { return x >= 0.f ? x : 0.2f * x; }
__device__ __forceinline__ float leaky01(float x) { return x >= 0.f ? x : 0.01f * x; }

// ---------------------------------------------------------------------------
// CSR build: histogram placement with fixed capacity. Self-loops NOT stored
// (handled implicitly in aggregation). Harness stages integer inputs as int32.
// ---------------------------------------------------------------------------
__global__ __launch_bounds__(256) void build_csr(const int* __restrict__ ei,
                                                 int* __restrict__ deg,
                                                 int* __restrict__ csr) {
    int e = blockIdx.x * 256 + threadIdx.x;
    if (e >= EE) return;
    int s = ei[e];         // edge_index[0][e]
    int d = ei[EE + e];    // edge_index[1][e]
    if ((unsigned)d >= NN || (unsigned)s >= NN) return;  // defensive
    int pos = atomicAdd(&deg[d], 1);
    if (pos < CAP) csr[d * CAP + pos] = s;
}

// ---------------------------------------------------------------------------
// Register-tiled GEMM: h = x @ W, x:[NN,K], W:[K,256], tile 128x128, BK=32.
// 256 threads, each owns 8x8 accs. h written as FP16 (halves gather bytes in
// the aggregate; logits al_s/al_d still from exact fp32 accs).
// ---------------------------------------------------------------------------
template <int K>
__global__ __launch_bounds__(256, 3) void gemm_gat(const float* __restrict__ x,
                                                   const float* __restrict__ W,
                                                   const float* __restrict__ a_src,
                                                   const float* __restrict__ a_dst,
                                                   __half* __restrict__ h_out,
                                                   float* __restrict__ al_s,
                                                   float* __restrict__ al_d) {
    __shared__ float Xs[32 * 128];   // [k][slot*8 + m&7], swizzled
    __shared__ float Ws[32 * 128];   // [k][n] linear
    const int t  = threadIdx.x;
    const int tc = t & 15;           // col group (8 cols each)
    const int tr = t >> 4;           // row group (8 rows each)
    const int r0 = blockIdx.x * 128;
    const int c0 = blockIdx.y * 128;

    float acc[8][8];
#pragma unroll
    for (int i = 0; i < 8; ++i)
#pragma unroll
        for (int j = 0; j < 8; ++j) acc[i][j] = 0.f;

    for (int k0 = 0; k0 < K; k0 += 32) {
        // ---- stage X tile: 128 rows x 32 k, store transposed+swizzled ----
#pragma unroll
        for (int jj = 0; jj < 4; ++jj) {
            int id = t + jj * 256;           // 0..1023
            int m  = id >> 3;                // 0..127
            int k4 = id & 7;                 // float4 index along k
            int row = r0 + m;
            row = row < NN ? row : NN - 1;   // clamp (stores are guarded later)
            float4 v = *(const float4*)(x + (size_t)row * K + k0 + k4 * 4);
#pragma unroll
            for (int c = 0; c < 4; ++c) {
                int k = k4 * 4 + c;
                int slot = (m >> 3) ^ (k >> 2);
                Xs[k * 128 + slot * 8 + (m & 7)] = ((const float*)&v)[c];
            }
        }
        // ---- stage W tile: 32 k x 128 n, linear ----
#pragma unroll
        for (int jj = 0; jj < 4; ++jj) {
            int id = t + jj * 256;
            int k  = id >> 5;                // 0..31
            int n4 = id & 31;                // 0..31
            float4 v = *(const float4*)(W + (size_t)(k0 + k) * 256 + c0 + n4 * 4);
            *(float4*)(Ws + k * 128 + n4 * 4) = v;
        }
        __syncthreads();

#pragma unroll
        for (int k = 0; k < 32; ++k) {
            int aslot = tr ^ (k >> 2);
            const float* ax = &Xs[k * 128 + aslot * 8];
            const float* bw = &Ws[k * 128 + tc * 8];
            float a0[8], b0[8];
            *(float4*)&a0[0] = *(const float4*)&ax[0];
            *(float4*)&a0[4] = *(const float4*)&ax[4];
            *(float4*)&b0[0] = *(const float4*)&bw[0];
            *(float4*)&b0[4] = *(const float4*)&bw[4];
#pragma unroll
            for (int i = 0; i < 8; ++i)
#pragma unroll
                for (int j = 0; j < 8; ++j)
                    acc[i][j] = fmaf(a0[i], b0[j], acc[i][j]);
        }
        __syncthreads();
    }

    // ---- epilogue: write h (fp16), fused al_s/al_d (fp32) ----
    const int colbase = c0 + tc * 8;
    const int head = colbase >> 6;   // 8 cols never straddle a head boundary
    float as_c[8], ad_c[8];
#pragma unroll
    for (int j = 0; j < 8; ++j) {
        as_c[j] = a_src[colbase + j];
        ad_c[j] = a_dst[colbase + j];
    }
#pragma unroll
    for (int i = 0; i < 8; ++i) {
        int row = r0 + tr * 8 + i;
        bool ok = row < NN;
        if (ok) {
            __half2 p0 = __floats2half2_rn(acc[i][0], acc[i][1]);
            __half2 p1 = __floats2half2_rn(acc[i][2], acc[i][3]);
            __half2 p2 = __floats2half2_rn(acc[i][4], acc[i][5]);
            __half2 p3 = __floats2half2_rn(acc[i][6], acc[i][7]);
            uint4 pk;
            pk.x = *(unsigned int*)&p0;
            pk.y = *(unsigned int*)&p1;
            pk.z = *(unsigned int*)&p2;
            pk.w = *(unsigned int*)&p3;
            *(uint4*)(h_out + (size_t)row * 256 + colbase) = pk;
        }
        float ps = 0.f, pd = 0.f;
#pragma unroll
        for (int j = 0; j < 8; ++j) {
            ps = fmaf(acc[i][j], as_c[j], ps);
            pd = fmaf(acc[i][j], ad_c[j], pd);
        }
#pragma unroll
        for (int off = 1; off <= 4; off <<= 1) {
            ps += __shfl_xor(ps, off, 64);
            pd += __shfl_xor(pd, off, 64);
        }
        if (ok && (tc & 7) == 0) {
            al_s[(size_t)row * 4 + head] = ps;
            al_d[(size_t)row * 4 + head] = pd;
        }
    }
}

// ---------------------------------------------------------------------------
// Per-dst segment softmax + aggregation. One wave per dst node.
// Lane j owns edge j (d<=64): computes alpha/e/coef ONCE, coef -> LDS.
// Channel remap: lane L owns flat channels 4L..4L+3 (head L>>4): gather is one
// dwordx2 (4 fp16) per lane per edge = 512B per row per wave.
// ---------------------------------------------------------------------------
struct Half4 { __half2 a, b; };

__global__ __launch_bounds__(256) void gat_aggregate(const __half* __restrict__ h_buf,
                                                     const float* __restrict__ al_s,
                                                     const float* __restrict__ al_d,
                                                     const int* __restrict__ deg,
                                                     const int* __restrict__ csr,
                                                     const float* __restrict__ bias,
                                                     float* __restrict__ xout) {
    __shared__ __align__(16) float els[4][64][4];   // [wave][edge][head] coef
    const int w    = threadIdx.x >> 6;
    const int lane = threadIdx.x & 63;
    const int n    = blockIdx.x * 4 + w;
    if (n >= NN) return;                 // grid is exact: never taken
    const int d = min(deg[n], CAP);

    float4 ad4 = *(const float4*)(al_d + (size_t)n * 4);
    float4 as4 = *(const float4*)(al_s + (size_t)n * 4);
    const float* adp = (const float*)&ad4;
    const float* asp = (const float*)&as4;

    float aself[4];
#pragma unroll
    for (int h = 0; h < 4; ++h) aself[h] = leaky02(asp[h] + adp[h]);

    // ---- lane j loads its edge and computes alpha ----
    int s_lane = 0;
    float a_lane[4];
    if (lane < d) {
        s_lane = csr[(size_t)n * CAP + lane];
        float4 s4 = *(const float4*)(al_s + (size_t)s_lane * 4);
        const float* sp = (const float*)&s4;
#pragma unroll
        for (int h = 0; h < 4; ++h) a_lane[h] = leaky02(sp[h] + adp[h]);
    } else {
#pragma unroll
        for (int h = 0; h < 4; ++h) a_lane[h] = -INFINITY;
    }

    // ---- max over edges + self ----
    float mx[4];
#pragma unroll
    for (int h = 0; h < 4; ++h) {
        mx[h] = fmaxf(aself[h], a_lane[h]);
#pragma unroll
        for (int off = 32; off; off >>= 1) mx[h] = fmaxf(mx[h], __shfl_xor(mx[h], off, 64));
    }

    // ---- e per edge (once), sum via tree, coef -> LDS ----
    float e[4], sm[4];
#pragma unroll
    for (int h = 0; h < 4; ++h) {
        e[h] = (lane < d) ? expf(a_lane[h] - mx[h]) : 0.f;
        sm[h] = e[h];
#pragma unroll
        for (int off = 32; off; off >>= 1) sm[h] += __shfl_xor(sm[h], off, 64);
    }
    float eself[4], inv[4];
    float4 coef;
    float* cf = (float*)&coef;
#pragma unroll
    for (int h = 0; h < 4; ++h) {
        eself[h] = expf(aself[h] - mx[h]);
        inv[h] = 1.f / (sm[h] + eself[h] + 1e-16f);
        cf[h] = e[h] * inv[h];
    }
    *(float4*)&els[w][lane][0] = coef;

    // ---- pass 3: lane owns flat channels 4L..4L+3 (head hh) ----
    const int hh = lane >> 4;
    const __half* __restrict__ hb = h_buf + (size_t)lane * 4;
    const float selfc = eself[hh] * inv[hh];
    Half4 hv = *(const Half4*)(hb + (size_t)n * 256);
    float2 f0 = __half22float2(hv.a);
    float2 f1 = __half22float2(hv.b);
    float acc0 = f0.x * selfc, acc1 = f0.y * selfc, acc2 = f1.x * selfc, acc3 = f1.y * selfc;

    for (int j = 0; j < d; ++j) {
        int s = __shfl(s_lane, j, 64);
        float cj = els[w][j][hh];
        Half4 hj = *(const Half4*)(hb + (size_t)s * 256);
        float2 g0 = __half22float2(hj.a);
        float2 g1 = __half22float2(hj.b);
        acc0 = fmaf(g0.x, cj, acc0);
        acc1 = fmaf(g0.y, cj, acc1);
        acc2 = fmaf(g1.x, cj, acc2);
        acc3 = fmaf(g1.y, cj, acc3);
    }

    // ---- head mean: lanes {L, L^16, L^32, L^48} hold same within-head chans
#pragma unroll
    for (int off = 16; off <= 32; off <<= 1) {
        acc0 += __shfl_xor(acc0, off, 64);
        acc1 += __shfl_xor(acc1, off, 64);
        acc2 += __shfl_xor(acc2, off, 64);
        acc3 += __shfl_xor(acc3, off, 64);
    }
    if (lane < 16) {
        float4 o;
        o.x = leaky01(acc0 * 0.25f + bias[lane * 4 + 0]);
        o.y = leaky01(acc1 * 0.25f + bias[lane * 4 + 1]);
        o.z = leaky01(acc2 * 0.25f + bias[lane * 4 + 2]);
        o.w = leaky01(acc3 * 0.25f + bias[lane * 4 + 3]);
        *(float4*)(xout + (size_t)n * 64 + lane * 4) = o;
    }
}

// ---------------------------------------------------------------------------
// Readout: one block per graph g; batch_index is sorted -> binary search.
// ---------------------------------------------------------------------------
__global__ __launch_bounds__(256) void readout(const float* __restrict__ x,
                                               const int* __restrict__ batch,
                                               float* __restrict__ gmp,
                                               float* __restrict__ gap) {
    int g = blockIdx.x;
    int a = 0, b = NN;
    while (a < b) { int m = (a + b) >> 1; if (batch[m] < g) a = m + 1; else b = m; }
    int lo = a;
    a = lo; b = NN;
    while (a < b) { int m = (a + b) >> 1; if (batch[m] < g + 1) a = m + 1; else b = m; }
    int hi = a;

    int t = threadIdx.x, c = t & 63, s = t >> 6;
    float mx = -INFINITY, sm = 0.f;
    for (int n = lo + s; n < hi; n += 4) {
        float v = x[(size_t)n * 64 + c];
        mx = fmaxf(mx, v);
        sm += v;
    }
    __shared__ float smx[256], ssm[256];
    smx[t] = mx; ssm[t] = sm;
    __syncthreads();
    if (t < 64) {
        mx = fmaxf(fmaxf(smx[t], smx[t + 64]), fmaxf(smx[t + 128], smx[t + 192]));
        sm = ssm[t] + ssm[t + 64] + ssm[t + 128] + ssm[t + 192];
        int cnt = hi - lo;
        gmp[g * 64 + t] = mx;
        gap[g * 64 + t] = sm / fmaxf((float)cnt, 1.0f);
    }
}

// ---------------------------------------------------------------------------
// Final MLP: one wave per graph.
// ---------------------------------------------------------------------------
__global__ __launch_bounds__(64) void mlp_readout(const float* __restrict__ gmp,
                                                  const float* __restrict__ gap,
                                                  const float* __restrict__ Wr1,
                                                  const float* __restrict__ br1,
                                                  const float* __restrict__ Wr2,
                                                  const float* __restrict__ br2,
                                                  float* __restrict__ out) {
    int g = blockIdx.x;
    int j = threadIdx.x;  // 0..63
    double acc = (double)br1[j];
    for (int i = 0; i < 64; ++i) acc += (double)gmp[g * 64 + i] * (double)Wr1[i * 64 + j];
    for (int i = 0; i < 64; ++i) acc += (double)gap[g * 64 + i] * (double)Wr1[(64 + i) * 64 + j];
    float v = (float)acc;
    v = v >= 0.f ? v : 0.01f * v;
    double tv = (double)v * (double)Wr2[j];
#pragma unroll
    for (int off = 32; off; off >>= 1) tv += __shfl_xor(tv, off, 64);
    if (j == 0) out[g] = (float)(tv + (double)br2[0]);
}

// ---------------------------------------------------------------------------
extern "C" void kernel_launch(void* const* d_in, const int* in_sizes, int n_in,
                              void* d_out, int out_size, void* d_ws, size_t ws_size,
                              hipStream_t stream) {
    const float* x   = (const float*)d_in[0];
    const int* ei    = (const int*)d_in[1];    // int inputs staged as int32
    // d_in[2] edge_attr unused
    const int* batch = (const int*)d_in[3];
    const float* W0  = (const float*)d_in[4];
    const float* as0 = (const float*)d_in[5];
    const float* ad0 = (const float*)d_in[6];
    const float* b0  = (const float*)d_in[7];
    const float* W1  = (const float*)d_in[8];
    const float* as1 = (const float*)d_in[9];
    const float* ad1 = (const float*)d_in[10];
    const float* b1  = (const float*)d_in[11];
    const float* W2  = (const float*)d_in[12];
    const float* as2 = (const float*)d_in[13];
    const float* ad2 = (const float*)d_in[14];
    const float* b2  = (const float*)d_in[15];
    const float* Wr1 = (const float*)d_in[16];
    const float* br1 = (const float*)d_in[17];
    const float* Wr2 = (const float*)d_in[18];
    const float* br2 = (const float*)d_in[19];
    float* out = (float*)d_out;

    // workspace layout
    __half* h_buf = (__half*)d_ws;                       // NN*256 halves (25.6MB)
    float* al_s  = (float*)(h_buf + (size_t)NN * 256);   // NN*4
    float* al_d  = al_s + (size_t)NN * 4;                // NN*4
    float* xbuf  = al_d + (size_t)NN * 4;                // NN*64
    float* gmp   = xbuf + (size_t)NN * 64;               // GG*64
    float* gap   = gmp + (size_t)GG * 64;                // GG*64
    int*   deg   = (int*)(gap + (size_t)GG * 64);        // NN
    int*   csr   = deg + NN;                             // NN*CAP

    hipMemsetAsync(deg, 0, NN * sizeof(int), stream);
    build_csr<<<(EE + 255) / 256, 256, 0, stream>>>(ei, deg, csr);

    const dim3 gemm_grid((NN + 127) / 128, 2);
    const int agg_grid = (NN + 3) / 4;

    // layer 0
    gemm_gat<FIN><<<gemm_grid, 256, 0, stream>>>(x, W0, as0, ad0, h_buf, al_s, al_d);
    gat_aggregate<<<agg_grid, 256, 0, stream>>>(h_buf, al_s, al_d, deg, csr, b0, xbuf);
    // layer 1
    gemm_gat<CC><<<gemm_grid, 256, 0, stream>>>(xbuf, W1, as1, ad1, h_buf, al_s, al_d);
    gat_aggregate<<<agg_grid, 256, 0, stream>>>(h_buf, al_s, al_d, deg, csr, b1, xbuf);
    // layer 2
    gemm_gat<CC><<<gemm_grid, 256, 0, stream>>>(xbuf, W2, as2, ad2, h_buf, al_s, al_d);
    gat_aggregate<<<agg_grid, 256, 0, stream>>>(h_buf, al_s, al_d, deg, csr, b2, xbuf);

    // readout
    readout<<<GG, 256, 0, stream>>>(xbuf, batch, gmp, gap);
    mlp_readout<<<GG, 64, 0, stream>>>(gmp, gap, Wr1, br1, Wr2, br2, out);
}

// Round 10
// 502.667 us; speedup vs baseline: 1.3579x; 1.0542x over previous
//
#include <hip/hip_runtime.h>
#include <hip/hip_bf16.h>
#include <hip/hip_fp16.h>

// Problem constants (fixed by the reference setup)
#define NN   50000
#define EE   800000
#define FIN  128
#define CC   64
#define HH   4
#define GG   512
#define CAP  64          // per-node CSR capacity (Poisson(16) in-degree; P(>64) ~ 2e-18)

__device__ __forceinline__ float leaky02(float x) { return x >= 0.f ? x : 0.2f * x; }
__device__ __forceinline__ float leaky01(float x) { return x >= 0.f ? x : 0.01f * x; }

// ---------------------------------------------------------------------------
// CSR build: histogram placement with fixed capacity. Self-loops NOT stored
// (handled implicitly in aggregation). Harness stages integer inputs as int32.
// ---------------------------------------------------------------------------
__global__ __launch_bounds__(256) void build_csr(const int* __restrict__ ei,
                                                 int* __restrict__ deg,
                                                 int* __restrict__ csr) {
    int e = blockIdx.x * 256 + threadIdx.x;
    if (e >= EE) return;
    int s = ei[e];         // edge_index[0][e]
    int d = ei[EE + e];    // edge_index[1][e]
    if ((unsigned)d >= NN || (unsigned)s >= NN) return;  // defensive
    int pos = atomicAdd(&deg[d], 1);
    if (pos < CAP) csr[d * CAP + pos] = s;
}

// ---------------------------------------------------------------------------
// Register-tiled GEMM: h = x @ W, x:[NN,K], W:[K,256], tile 128x128, BK=32.
// 256 threads, each owns 8x8 accs. h written as FP16.
// ---------------------------------------------------------------------------
template <int K>
__global__ __launch_bounds__(256, 3) void gemm_gat(const float* __restrict__ x,
                                                   const float* __restrict__ W,
                                                   const float* __restrict__ a_src,
                                                   const float* __restrict__ a_dst,
                                                   __half* __restrict__ h_out,
                                                   float* __restrict__ al_s,
                                                   float* __restrict__ al_d) {
    __shared__ float Xs[32 * 128];   // [k][slot*8 + m&7], swizzled
    __shared__ float Ws[32 * 128];   // [k][n] linear
    const int t  = threadIdx.x;
    const int tc = t & 15;           // col group (8 cols each)
    const int tr = t >> 4;           // row group (8 rows each)
    const int r0 = blockIdx.x * 128;
    const int c0 = blockIdx.y * 128;

    float acc[8][8];
#pragma unroll
    for (int i = 0; i < 8; ++i)
#pragma unroll
        for (int j = 0; j < 8; ++j) acc[i][j] = 0.f;

    for (int k0 = 0; k0 < K; k0 += 32) {
        // ---- stage X tile: 128 rows x 32 k, store transposed+swizzled ----
#pragma unroll
        for (int jj = 0; jj < 4; ++jj) {
            int id = t + jj * 256;           // 0..1023
            int m  = id >> 3;                // 0..127
            int k4 = id & 7;                 // float4 index along k
            int row = r0 + m;
            row = row < NN ? row : NN - 1;   // clamp (stores are guarded later)
            float4 v = *(const float4*)(x + (size_t)row * K + k0 + k4 * 4);
#pragma unroll
            for (int c = 0; c < 4; ++c) {
                int k = k4 * 4 + c;
                int slot = (m >> 3) ^ (k >> 2);
                Xs[k * 128 + slot * 8 + (m & 7)] = ((const float*)&v)[c];
            }
        }
        // ---- stage W tile: 32 k x 128 n, linear ----
#pragma unroll
        for (int jj = 0; jj < 4; ++jj) {
            int id = t + jj * 256;
            int k  = id >> 5;                // 0..31
            int n4 = id & 31;                // 0..31
            float4 v = *(const float4*)(W + (size_t)(k0 + k) * 256 + c0 + n4 * 4);
            *(float4*)(Ws + k * 128 + n4 * 4) = v;
        }
        __syncthreads();

#pragma unroll
        for (int k = 0; k < 32; ++k) {
            int aslot = tr ^ (k >> 2);
            const float* ax = &Xs[k * 128 + aslot * 8];
            const float* bw = &Ws[k * 128 + tc * 8];
            float a0[8], b0[8];
            *(float4*)&a0[0] = *(const float4*)&ax[0];
            *(float4*)&a0[4] = *(const float4*)&ax[4];
            *(float4*)&b0[0] = *(const float4*)&bw[0];
            *(float4*)&b0[4] = *(const float4*)&bw[4];
#pragma unroll
            for (int i = 0; i < 8; ++i)
#pragma unroll
                for (int j = 0; j < 8; ++j)
                    acc[i][j] = fmaf(a0[i], b0[j], acc[i][j]);
        }
        __syncthreads();
    }

    // ---- epilogue: write h (fp16), fused al_s/al_d (fp32) ----
    const int colbase = c0 + tc * 8;
    const int head = colbase >> 6;   // 8 cols never straddle a head boundary
    float as_c[8], ad_c[8];
#pragma unroll
    for (int j = 0; j < 8; ++j) {
        as_c[j] = a_src[colbase + j];
        ad_c[j] = a_dst[colbase + j];
    }
#pragma unroll
    for (int i = 0; i < 8; ++i) {
        int row = r0 + tr * 8 + i;
        bool ok = row < NN;
        if (ok) {
            __half2 p0 = __floats2half2_rn(acc[i][0], acc[i][1]);
            __half2 p1 = __floats2half2_rn(acc[i][2], acc[i][3]);
            __half2 p2 = __floats2half2_rn(acc[i][4], acc[i][5]);
            __half2 p3 = __floats2half2_rn(acc[i][6], acc[i][7]);
            uint4 pk;
            pk.x = *(unsigned int*)&p0;
            pk.y = *(unsigned int*)&p1;
            pk.z = *(unsigned int*)&p2;
            pk.w = *(unsigned int*)&p3;
            *(uint4*)(h_out + (size_t)row * 256 + colbase) = pk;
        }
        float ps = 0.f, pd = 0.f;
#pragma unroll
        for (int j = 0; j < 8; ++j) {
            ps = fmaf(acc[i][j], as_c[j], ps);
            pd = fmaf(acc[i][j], ad_c[j], pd);
        }
#pragma unroll
        for (int off = 1; off <= 4; off <<= 1) {
            ps += __shfl_xor(ps, off, 64);
            pd += __shfl_xor(pd, off, 64);
        }
        if (ok && (tc & 7) == 0) {
            al_s[(size_t)row * 4 + head] = ps;
            al_d[(size_t)row * 4 + head] = pd;
        }
    }
}

// ---------------------------------------------------------------------------
// Per-dst segment softmax + aggregation. One wave per dst node.
// Softmax (fp32): lane j owns edge j; coef written to LDS as dup'd half2,
// virtual row 0 = self-loop. Message pass: lane half q=lane>>5 processes
// virtual row 2t+q; lane m=lane&31 owns 8 channels (head m>>3) -> one
// dwordx4 (8 fp16) per lane, 1KB per wave instruction (2 rows), fp16 pk-fma
// accumulate. Final: xor-32 combine halves, fp32 head-mean via xor-8/16.
// ---------------------------------------------------------------------------
struct Half8 { __half2 h[4]; };

__global__ __launch_bounds__(256) void gat_aggregate(const __half* __restrict__ h_buf,
                                                     const float* __restrict__ al_s,
                                                     const float* __restrict__ al_d,
                                                     const int* __restrict__ deg,
                                                     const int* __restrict__ csr,
                                                     const float* __restrict__ bias,
                                                     float* __restrict__ xout) {
    __shared__ __align__(16) __half2 els[4][66][4];   // [wave][virtual row][head]
    const int w    = threadIdx.x >> 6;
    const int lane = threadIdx.x & 63;
    const int n    = blockIdx.x * 4 + w;    // grid exact: n < NN always
    const int d = min(deg[n], CAP);

    float4 ad4 = *(const float4*)(al_d + (size_t)n * 4);
    float4 as4 = *(const float4*)(al_s + (size_t)n * 4);
    const float* adp = (const float*)&ad4;
    const float* asp = (const float*)&as4;

    float aself[4];
#pragma unroll
    for (int h = 0; h < 4; ++h) aself[h] = leaky02(asp[h] + adp[h]);

    // ---- lane j loads its edge and computes alpha ----
    int s_lane = 0;
    float a_lane[4];
    if (lane < d) {
        s_lane = csr[(size_t)n * CAP + lane];
        float4 s4 = *(const float4*)(al_s + (size_t)s_lane * 4);
        const float* sp = (const float*)&s4;
#pragma unroll
        for (int h = 0; h < 4; ++h) a_lane[h] = leaky02(sp[h] + adp[h]);
    } else {
#pragma unroll
        for (int h = 0; h < 4; ++h) a_lane[h] = -INFINITY;
    }

    // ---- max over edges + self ----
    float mx[4];
#pragma unroll
    for (int h = 0; h < 4; ++h) {
        mx[h] = fmaxf(aself[h], a_lane[h]);
#pragma unroll
        for (int off = 32; off; off >>= 1) mx[h] = fmaxf(mx[h], __shfl_xor(mx[h], off, 64));
    }

    // ---- e per edge (once), sum via tree ----
    float e[4], sm[4];
#pragma unroll
    for (int h = 0; h < 4; ++h) {
        e[h] = (lane < d) ? expf(a_lane[h] - mx[h]) : 0.f;
        sm[h] = e[h];
#pragma unroll
        for (int off = 32; off; off >>= 1) sm[h] += __shfl_xor(sm[h], off, 64);
    }
    float eself[4], inv[4];
#pragma unroll
    for (int h = 0; h < 4; ++h) {
        eself[h] = expf(aself[h] - mx[h]);
        inv[h] = 1.f / (sm[h] + eself[h] + 1e-16f);
    }
    // coef -> LDS (dup'd half2). virtual row lane+1 = edge lane; row 0 = self.
    if (lane < d) {
#pragma unroll
        for (int h = 0; h < 4; ++h) {
            float c = e[h] * inv[h];
            els[w][lane + 1][h] = __floats2half2_rn(c, c);
        }
    }
    if (lane == 0) {
#pragma unroll
        for (int h = 0; h < 4; ++h) {
            float c = eself[h] * inv[h];
            els[w][0][h] = __floats2half2_rn(c, c);
        }
    }

    // ---- message pass: 2 virtual rows per iteration ----
    const int q    = lane >> 5;          // wave half
    const int m    = lane & 31;          // row-lane
    const int head = m >> 3;             // 0..3
    const __half* __restrict__ hb = h_buf + m * 8;   // channel base 8m

    __half2 z = __floats2half2_rn(0.f, 0.f);
    __half2 acc0 = z, acc1 = z, acc2 = z, acc3 = z;
    const int count = d + 1;             // +1 for self (virtual row 0)
    for (int t2 = 0; 2 * t2 < count; ++t2) {
        int v = 2 * t2 + q;
        int vi = v > 0 ? v - 1 : 0;
        int s = __shfl(s_lane, vi, 64);
        s = v == 0 ? n : s;
        if (v < count) {
            __half2 c2 = els[w][v][head];
            Half8 r = *(const Half8*)(hb + (size_t)s * 256);
            acc0 = __hfma2(r.h[0], c2, acc0);
            acc1 = __hfma2(r.h[1], c2, acc1);
            acc2 = __hfma2(r.h[2], c2, acc2);
            acc3 = __hfma2(r.h[3], c2, acc3);
        }
    }

    // ---- combine the two halves (lane L, L^32 hold same channels) ----
    int i0 = __shfl_xor(*(int*)&acc0, 32, 64);
    int i1 = __shfl_xor(*(int*)&acc1, 32, 64);
    int i2 = __shfl_xor(*(int*)&acc2, 32, 64);
    int i3 = __shfl_xor(*(int*)&acc3, 32, 64);
    acc0 = __hadd2(acc0, *(__half2*)&i0);
    acc1 = __hadd2(acc1, *(__half2*)&i1);
    acc2 = __hadd2(acc2, *(__half2*)&i2);
    acc3 = __hadd2(acc3, *(__half2*)&i3);

    // ---- to fp32, head mean (lanes m, m^8, m^16, m^24 hold heads 0..3) ----
    float ch[8];
    float2 f;
    f = __half22float2(acc0); ch[0] = f.x; ch[1] = f.y;
    f = __half22float2(acc1); ch[2] = f.x; ch[3] = f.y;
    f = __half22float2(acc2); ch[4] = f.x; ch[5] = f.y;
    f = __half22float2(acc3); ch[6] = f.x; ch[7] = f.y;
#pragma unroll
    for (int k = 0; k < 8; ++k) {
        ch[k] += __shfl_xor(ch[k], 8, 64);
        ch[k] += __shfl_xor(ch[k], 16, 64);
    }
    if (lane < 8) {
        float4 o0, o1;
        o0.x = leaky01(ch[0] * 0.25f + bias[lane * 8 + 0]);
        o0.y = leaky01(ch[1] * 0.25f + bias[lane * 8 + 1]);
        o0.z = leaky01(ch[2] * 0.25f + bias[lane * 8 + 2]);
        o0.w = leaky01(ch[3] * 0.25f + bias[lane * 8 + 3]);
        o1.x = leaky01(ch[4] * 0.25f + bias[lane * 8 + 4]);
        o1.y = leaky01(ch[5] * 0.25f + bias[lane * 8 + 5]);
        o1.z = leaky01(ch[6] * 0.25f + bias[lane * 8 + 6]);
        o1.w = leaky01(ch[7] * 0.25f + bias[lane * 8 + 7]);
        *(float4*)(xout + (size_t)n * 64 + lane * 8)     = o0;
        *(float4*)(xout + (size_t)n * 64 + lane * 8 + 4) = o1;
    }
}

// ---------------------------------------------------------------------------
// Readout: one block per graph g; batch_index is sorted -> binary search.
// ---------------------------------------------------------------------------
__global__ __launch_bounds__(256) void readout(const float* __restrict__ x,
                                               const int* __restrict__ batch,
                                               float* __restrict__ gmp,
                                               float* __restrict__ gap) {
    int g = blockIdx.x;
    int a = 0, b = NN;
    while (a < b) { int m = (a + b) >> 1; if (batch[m] < g) a = m + 1; else b = m; }
    int lo = a;
    a = lo; b = NN;
    while (a < b) { int m = (a + b) >> 1; if (batch[m] < g + 1) a = m + 1; else b = m; }
    int hi = a;

    int t = threadIdx.x, c = t & 63, s = t >> 6;
    float mx = -INFINITY, sm = 0.f;
    for (int n = lo + s; n < hi; n += 4) {
        float v = x[(size_t)n * 64 + c];
        mx = fmaxf(mx, v);
        sm += v;
    }
    __shared__ float smx[256], ssm[256];
    smx[t] = mx; ssm[t] = sm;
    __syncthreads();
    if (t < 64) {
        mx = fmaxf(fmaxf(smx[t], smx[t + 64]), fmaxf(smx[t + 128], smx[t + 192]));
        sm = ssm[t] + ssm[t + 64] + ssm[t + 128] + ssm[t + 192];
        int cnt = hi - lo;
        gmp[g * 64 + t] = mx;
        gap[g * 64 + t] = sm / fmaxf((float)cnt, 1.0f);
    }
}

// ---------------------------------------------------------------------------
// Final MLP: one wave per graph.
// ---------------------------------------------------------------------------
__global__ __launch_bounds__(64) void mlp_readout(const float* __restrict__ gmp,
                                                  const float* __restrict__ gap,
                                                  const float* __restrict__ Wr1,
                                                  const float* __restrict__ br1,
                                                  const float* __restrict__ Wr2,
                                                  const float* __restrict__ br2,
                                                  float* __restrict__ out) {
    int g = blockIdx.x;
    int j = threadIdx.x;  // 0..63
    double acc = (double)br1[j];
    for (int i = 0; i < 64; ++i) acc += (double)gmp[g * 64 + i] * (double)Wr1[i * 64 + j];
    for (int i = 0; i < 64; ++i) acc += (double)gap[g * 64 + i] * (double)Wr1[(64 + i) * 64 + j];
    float v = (float)acc;
    v = v >= 0.f ? v : 0.01f * v;
    double tv = (double)v * (double)Wr2[j];
#pragma unroll
    for (int off = 32; off; off >>= 1) tv += __shfl_xor(tv, off, 64);
    if (j == 0) out[g] = (float)(tv + (double)br2[0]);
}

// ---------------------------------------------------------------------------
extern "C" void kernel_launch(void* const* d_in, const int* in_sizes, int n_in,
                              void* d_out, int out_size, void* d_ws, size_t ws_size,
                              hipStream_t stream) {
    const float* x   = (const float*)d_in[0];
    const int* ei    = (const int*)d_in[1];    // int inputs staged as int32
    // d_in[2] edge_attr unused
    const int* batch = (const int*)d_in[3];
    const float* W0  = (const float*)d_in[4];
    const float* as0 = (const float*)d_in[5];
    const float* ad0 = (const float*)d_in[6];
    const float* b0  = (const float*)d_in[7];
    const float* W1  = (const float*)d_in[8];
    const float* as1 = (const float*)d_in[9];
    const float* ad1 = (const float*)d_in[10];
    const float* b1  = (const float*)d_in[11];
    const float* W2  = (const float*)d_in[12];
    const float* as2 = (const float*)d_in[13];
    const float* ad2 = (const float*)d_in[14];
    const float* b2  = (const float*)d_in[15];
    const float* Wr1 = (const float*)d_in[16];
    const float* br1 = (const float*)d_in[17];
    const float* Wr2 = (const float*)d_in[18];
    const float* br2 = (const float*)d_in[19];
    float* out = (float*)d_out;

    // workspace layout
    __half* h_buf = (__half*)d_ws;                       // NN*256 halves (25.6MB)
    float* al_s  = (float*)(h_buf + (size_t)NN * 256);   // NN*4
    float* al_d  = al_s + (size_t)NN * 4;                // NN*4
    float* xbuf  = al_d + (size_t)NN * 4;                // NN*64
    float* gmp   = xbuf + (size_t)NN * 64;               // GG*64
    float* gap   = gmp + (size_t)GG * 64;                // GG*64
    int*   deg   = (int*)(gap + (size_t)GG * 64);        // NN
    int*   csr   = deg + NN;                             // NN*CAP

    hipMemsetAsync(deg, 0, NN * sizeof(int), stream);
    build_csr<<<(EE + 255) / 256, 256, 0, stream>>>(ei, deg, csr);

    const dim3 gemm_grid((NN + 127) / 128, 2);
    const int agg_grid = (NN + 3) / 4;

    // layer 0
    gemm_gat<FIN><<<gemm_grid, 256, 0, stream>>>(x, W0, as0, ad0, h_buf, al_s, al_d);
    gat_aggregate<<<agg_grid, 256, 0, stream>>>(h_buf, al_s, al_d, deg, csr, b0, xbuf);
    // layer 1
    gemm_gat<CC><<<gemm_grid, 256, 0, stream>>>(xbuf, W1, as1, ad1, h_buf, al_s, al_d);
    gat_aggregate<<<agg_grid, 256, 0, stream>>>(h_buf, al_s, al_d, deg, csr, b1, xbuf);
    // layer 2
    gemm_gat<CC><<<gemm_grid, 256, 0, stream>>>(xbuf, W2, as2, ad2, h_buf, al_s, al_d);
    gat_aggregate<<<agg_grid, 256, 0, stream>>>(h_buf, al_s, al_d, deg, csr, b2, xbuf);

    // readout
    readout<<<GG, 256, 0, stream>>>(xbuf, batch, gmp, gap);
    mlp_readout<<<GG, 64, 0, stream>>>(gmp, gap, Wr1, br1, Wr2, br2, out);
}

// Round 11
// 498.262 us; speedup vs baseline: 1.3699x; 1.0088x over previous
//
#include <hip/hip_runtime.h>
#include <hip/hip_bf16.h>
#include <hip/hip_fp16.h>

// Problem constants (fixed by the reference setup)
#define NN   50000
#define EE   800000
#define FIN  128
#define CC   64
#define HH   4
#define GG   512
#define CAP  64          // per-node CSR capacity (Poisson(16) in-degree; P(>64) ~ 2e-18)

typedef _Float16 f16x8 __attribute__((ext_vector_type(8)));
typedef float    f32x4 __attribute__((ext_vector_type(4)));

__device__ __forceinline__ float leaky02(float x) { return x >= 0.f ? x : 0.2f * x; }
__device__ __forceinline__ float leaky01(float x) { return x >= 0.f ? x : 0.01f * x; }

// ---------------------------------------------------------------------------
// CSR build: histogram placement with fixed capacity. Self-loops implicit.
// ---------------------------------------------------------------------------
__global__ __launch_bounds__(256) void build_csr(const int* __restrict__ ei,
                                                 int* __restrict__ deg,
                                                 int* __restrict__ csr) {
    int e = blockIdx.x * 256 + threadIdx.x;
    if (e >= EE) return;
    int s = ei[e];
    int d = ei[EE + e];
    if ((unsigned)d >= NN || (unsigned)s >= NN) return;
    int pos = atomicAdd(&deg[d], 1);
    if (pos < CAP) csr[d * CAP + pos] = s;
}

// ---------------------------------------------------------------------------
// fp32 -> (hi, lo) fp16 split, elementwise. n divisible by 8.
// ---------------------------------------------------------------------------
__global__ __launch_bounds__(256) void convert_x(const float* __restrict__ x,
                                                 __half* __restrict__ xh,
                                                 __half* __restrict__ xl,
                                                 int n) {
    int i = (blockIdx.x * 256 + threadIdx.x) * 8;
    if (i >= n) return;
    float v[8];
    *(float4*)&v[0] = *(const float4*)(x + i);
    *(float4*)&v[4] = *(const float4*)(x + i + 4);
    __half hi[8], lo[8];
#pragma unroll
    for (int j = 0; j < 8; ++j) {
        hi[j] = __float2half_rn(v[j]);
        lo[j] = __float2half_rn(v[j] - __half2float(hi[j]));
    }
    *(uint4*)(xh + i) = *(uint4*)hi;
    *(uint4*)(xl + i) = *(uint4*)lo;
}

// ---------------------------------------------------------------------------
// Pack W [K x 256] fp32 into MFMA B-fragment order (hi/lo fp16):
// Wp[((kc*16 + c)*64 + lane)*8 + j] = W[kc*32 + (lane>>4)*8 + j][c*16 + (lane&15)]
// ---------------------------------------------------------------------------
__global__ __launch_bounds__(256) void convert_w(const float* __restrict__ W,
                                                 __half* __restrict__ wph,
                                                 __half* __restrict__ wpl,
                                                 int K) {
    int id = blockIdx.x * 256 + threadIdx.x;
    int total = (K / 32) * 16 * 64;
    if (id >= total) return;
    int lane = id & 63;
    int c    = (id >> 6) & 15;
    int kc   = id >> 10;
    int kbase = kc * 32 + (lane >> 4) * 8;
    int col   = c * 16 + (lane & 15);
    __half hi[8], lo[8];
#pragma unroll
    for (int j = 0; j < 8; ++j) {
        float v = W[(size_t)(kbase + j) * 256 + col];
        hi[j] = __float2half_rn(v);
        lo[j] = __float2half_rn(v - __half2float(hi[j]));
    }
    *(uint4*)(wph + (size_t)id * 8) = *(uint4*)hi;
    *(uint4*)(wpl + (size_t)id * 8) = *(uint4*)lo;
}

// ---------------------------------------------------------------------------
// MFMA GEMM (Markidis 3-mul fp16 split = fp32 quality): h = X @ W.
// X:[NN,K] as hi/lo fp16 row-major; W pre-packed fragments. Block 256 = 4
// waves; wave owns 16 rows x 256 cols (16 accs of 16x16). A frag: row=lane&15,
// k=(lane>>4)*8+j (one 16B load). C frag: col=lane&15, row=(lane>>4)*4+reg
// (m89-verified). Fused al_s/al_d epilogue via low-4-bit shfl reduce.
// ---------------------------------------------------------------------------
template <int K>
__global__ __launch_bounds__(256) void gemm_mfma(const __half* __restrict__ xh,
                                                 const __half* __restrict__ xl,
                                                 const __half* __restrict__ wph,
                                                 const __half* __restrict__ wpl,
                                                 const float* __restrict__ a_src,
                                                 const float* __restrict__ a_dst,
                                                 __half* __restrict__ h_out,
                                                 float* __restrict__ al_s,
                                                 float* __restrict__ al_d) {
    const int t    = threadIdx.x;
    const int w    = t >> 6;
    const int lane = t & 63;
    const int r0   = blockIdx.x * 64 + w * 16;     // wave row base
    const int colL = lane & 15;
    const int rowg = lane >> 4;
    int arow = r0 + colL;                           // A row = lane&15
    arow = arow < NN ? arow : NN - 1;               // clamp (stores guarded)
    const int koff = rowg * 8;

    f32x4 acc[16];
#pragma unroll
    for (int c = 0; c < 16; ++c) acc[c] = (f32x4){0.f, 0.f, 0.f, 0.f};

    for (int kc = 0; kc < K / 32; ++kc) {
        f16x8 ah = *(const f16x8*)(xh + (size_t)arow * K + kc * 32 + koff);
        f16x8 al = *(const f16x8*)(xl + (size_t)arow * K + kc * 32 + koff);
        const __half* bbase_h = wph + ((size_t)(kc * 16) * 64 + lane) * 8;
        const __half* bbase_l = wpl + ((size_t)(kc * 16) * 64 + lane) * 8;
#pragma unroll
        for (int c = 0; c < 16; ++c) {
            f16x8 bh = *(const f16x8*)(bbase_h + c * 512);
            f16x8 bl = *(const f16x8*)(bbase_l + c * 512);
            acc[c] = __builtin_amdgcn_mfma_f32_16x16x32_f16(ah, bh, acc[c], 0, 0, 0);
            acc[c] = __builtin_amdgcn_mfma_f32_16x16x32_f16(al, bh, acc[c], 0, 0, 0);
            acc[c] = __builtin_amdgcn_mfma_f32_16x16x32_f16(ah, bl, acc[c], 0, 0, 0);
        }
    }

    // ---- epilogue: h fp16 store + fused attention logits ----
    float aps[4][4], apd[4][4];   // [reg r][head]
#pragma unroll
    for (int r = 0; r < 4; ++r)
#pragma unroll
        for (int h = 0; h < 4; ++h) { aps[r][h] = 0.f; apd[r][h] = 0.f; }

#pragma unroll
    for (int c = 0; c < 16; ++c) {
        const int col = c * 16 + colL;
        const float as = a_src[col];
        const float ad = a_dst[col];
        const int hh = c >> 2;
#pragma unroll
        for (int r = 0; r < 4; ++r) {
            const int row = r0 + rowg * 4 + r;
            const float v = acc[c][r];
            if (row < NN) h_out[(size_t)row * 256 + col] = __float2half_rn(v);
            aps[r][hh] = fmaf(v, as, aps[r][hh]);
            apd[r][hh] = fmaf(v, ad, apd[r][hh]);
        }
    }
#pragma unroll
    for (int r = 0; r < 4; ++r)
#pragma unroll
        for (int h = 0; h < 4; ++h) {
            float s = aps[r][h], d = apd[r][h];
#pragma unroll
            for (int off = 1; off <= 8; off <<= 1) {
                s += __shfl_xor(s, off, 64);
                d += __shfl_xor(d, off, 64);
            }
            aps[r][h] = s; apd[r][h] = d;
        }
    if (colL == 0) {
#pragma unroll
        for (int r = 0; r < 4; ++r) {
            const int row = r0 + rowg * 4 + r;
            if (row < NN) {
#pragma unroll
                for (int h = 0; h < 4; ++h) {
                    al_s[(size_t)row * 4 + h] = aps[r][h];
                    al_d[(size_t)row * 4 + h] = apd[r][h];
                }
            }
        }
    }
}

// ---------------------------------------------------------------------------
// Per-dst segment softmax + aggregation (unchanged core from round 10).
// Output: hi/lo fp16 split of leaky(mean+bias) for the next layer's MFMA GEMM.
// ---------------------------------------------------------------------------
struct Half8 { __half2 h[4]; };

__global__ __launch_bounds__(256) void gat_aggregate(const __half* __restrict__ h_buf,
                                                     const float* __restrict__ al_s,
                                                     const float* __restrict__ al_d,
                                                     const int* __restrict__ deg,
                                                     const int* __restrict__ csr,
                                                     const float* __restrict__ bias,
                                                     __half* __restrict__ xb_hi,
                                                     __half* __restrict__ xb_lo) {
    __shared__ __align__(16) __half2 els[4][66][4];   // [wave][virtual row][head]
    const int w    = threadIdx.x >> 6;
    const int lane = threadIdx.x & 63;
    const int n    = blockIdx.x * 4 + w;    // grid exact
    const int d = min(deg[n], CAP);

    float4 ad4 = *(const float4*)(al_d + (size_t)n * 4);
    float4 as4 = *(const float4*)(al_s + (size_t)n * 4);
    const float* adp = (const float*)&ad4;
    const float* asp = (const float*)&as4;

    float aself[4];
#pragma unroll
    for (int h = 0; h < 4; ++h) aself[h] = leaky02(asp[h] + adp[h]);

    int s_lane = 0;
    float a_lane[4];
    if (lane < d) {
        s_lane = csr[(size_t)n * CAP + lane];
        float4 s4 = *(const float4*)(al_s + (size_t)s_lane * 4);
        const float* sp = (const float*)&s4;
#pragma unroll
        for (int h = 0; h < 4; ++h) a_lane[h] = leaky02(sp[h] + adp[h]);
    } else {
#pragma unroll
        for (int h = 0; h < 4; ++h) a_lane[h] = -INFINITY;
    }

    float mx[4];
#pragma unroll
    for (int h = 0; h < 4; ++h) {
        mx[h] = fmaxf(aself[h], a_lane[h]);
#pragma unroll
        for (int off = 32; off; off >>= 1) mx[h] = fmaxf(mx[h], __shfl_xor(mx[h], off, 64));
    }

    float e[4], sm[4];
#pragma unroll
    for (int h = 0; h < 4; ++h) {
        e[h] = (lane < d) ? expf(a_lane[h] - mx[h]) : 0.f;
        sm[h] = e[h];
#pragma unroll
        for (int off = 32; off; off >>= 1) sm[h] += __shfl_xor(sm[h], off, 64);
    }
    float eself[4], inv[4];
#pragma unroll
    for (int h = 0; h < 4; ++h) {
        eself[h] = expf(aself[h] - mx[h]);
        inv[h] = 1.f / (sm[h] + eself[h] + 1e-16f);
    }
    if (lane < d) {
#pragma unroll
        for (int h = 0; h < 4; ++h) {
            float c = e[h] * inv[h];
            els[w][lane + 1][h] = __floats2half2_rn(c, c);
        }
    }
    if (lane == 0) {
#pragma unroll
        for (int h = 0; h < 4; ++h) {
            float c = eself[h] * inv[h];
            els[w][0][h] = __floats2half2_rn(c, c);
        }
    }

    const int q    = lane >> 5;
    const int m    = lane & 31;
    const int head = m >> 3;
    const __half* __restrict__ hb = h_buf + m * 8;

    __half2 z = __floats2half2_rn(0.f, 0.f);
    __half2 acc0 = z, acc1 = z, acc2 = z, acc3 = z;
    const int count = d + 1;
    for (int t2 = 0; 2 * t2 < count; ++t2) {
        int v = 2 * t2 + q;
        int vi = v > 0 ? v - 1 : 0;
        int s = __shfl(s_lane, vi, 64);
        s = v == 0 ? n : s;
        if (v < count) {
            __half2 c2 = els[w][v][head];
            Half8 r = *(const Half8*)(hb + (size_t)s * 256);
            acc0 = __hfma2(r.h[0], c2, acc0);
            acc1 = __hfma2(r.h[1], c2, acc1);
            acc2 = __hfma2(r.h[2], c2, acc2);
            acc3 = __hfma2(r.h[3], c2, acc3);
        }
    }

    int i0 = __shfl_xor(*(int*)&acc0, 32, 64);
    int i1 = __shfl_xor(*(int*)&acc1, 32, 64);
    int i2 = __shfl_xor(*(int*)&acc2, 32, 64);
    int i3 = __shfl_xor(*(int*)&acc3, 32, 64);
    acc0 = __hadd2(acc0, *(__half2*)&i0);
    acc1 = __hadd2(acc1, *(__half2*)&i1);
    acc2 = __hadd2(acc2, *(__half2*)&i2);
    acc3 = __hadd2(acc3, *(__half2*)&i3);

    float ch[8];
    float2 f;
    f = __half22float2(acc0); ch[0] = f.x; ch[1] = f.y;
    f = __half22float2(acc1); ch[2] = f.x; ch[3] = f.y;
    f = __half22float2(acc2); ch[4] = f.x; ch[5] = f.y;
    f = __half22float2(acc3); ch[6] = f.x; ch[7] = f.y;
#pragma unroll
    for (int k = 0; k < 8; ++k) {
        ch[k] += __shfl_xor(ch[k], 8, 64);
        ch[k] += __shfl_xor(ch[k], 16, 64);
    }
    if (lane < 8) {
        __align__(16) __half hi8[8], lo8[8];
#pragma unroll
        for (int k = 0; k < 8; ++k) {
            float o = leaky01(ch[k] * 0.25f + bias[lane * 8 + k]);
            __half hv = __float2half_rn(o);
            hi8[k] = hv;
            lo8[k] = __float2half_rn(o - __half2float(hv));
        }
        *(uint4*)(xb_hi + (size_t)n * 64 + lane * 8) = *(uint4*)hi8;
        *(uint4*)(xb_lo + (size_t)n * 64 + lane * 8) = *(uint4*)lo8;
    }
}

// ---------------------------------------------------------------------------
// Readout: one block per graph g; batch sorted -> binary search. Reads fp16 hi.
// ---------------------------------------------------------------------------
__global__ __launch_bounds__(256) void readout(const __half* __restrict__ x,
                                               const int* __restrict__ batch,
                                               float* __restrict__ gmp,
                                               float* __restrict__ gap) {
    int g = blockIdx.x;
    int a = 0, b = NN;
    while (a < b) { int m = (a + b) >> 1; if (batch[m] < g) a = m + 1; else b = m; }
    int lo = a;
    a = lo; b = NN;
    while (a < b) { int m = (a + b) >> 1; if (batch[m] < g + 1) a = m + 1; else b = m; }
    int hi = a;

    int t = threadIdx.x, c = t & 63, s = t >> 6;
    float mx = -INFINITY, sm = 0.f;
    for (int n = lo + s; n < hi; n += 4) {
        float v = __half2float(x[(size_t)n * 64 + c]);
        mx = fmaxf(mx, v);
        sm += v;
    }
    __shared__ float smx[256], ssm[256];
    smx[t] = mx; ssm[t] = sm;
    __syncthreads();
    if (t < 64) {
        mx = fmaxf(fmaxf(smx[t], smx[t + 64]), fmaxf(smx[t + 128], smx[t + 192]));
        sm = ssm[t] + ssm[t + 64] + ssm[t + 128] + ssm[t + 192];
        int cnt = hi - lo;
        gmp[g * 64 + t] = mx;
        gap[g * 64 + t] = sm / fmaxf((float)cnt, 1.0f);
    }
}

// ---------------------------------------------------------------------------
// Final MLP: one wave per graph.
// ---------------------------------------------------------------------------
__global__ __launch_bounds__(64) void mlp_readout(const float* __restrict__ gmp,
                                                  const float* __restrict__ gap,
                                                  const float* __restrict__ Wr1,
                                                  const float* __restrict__ br1,
                                                  const float* __restrict__ Wr2,
                                                  const float* __restrict__ br2,
                                                  float* __restrict__ out) {
    int g = blockIdx.x;
    int j = threadIdx.x;
    double acc = (double)br1[j];
    for (int i = 0; i < 64; ++i) acc += (double)gmp[g * 64 + i] * (double)Wr1[i * 64 + j];
    for (int i = 0; i < 64; ++i) acc += (double)gap[g * 64 + i] * (double)Wr1[(64 + i) * 64 + j];
    float v = (float)acc;
    v = v >= 0.f ? v : 0.01f * v;
    double tv = (double)v * (double)Wr2[j];
#pragma unroll
    for (int off = 32; off; off >>= 1) tv += __shfl_xor(tv, off, 64);
    if (j == 0) out[g] = (float)(tv + (double)br2[0]);
}

// ---------------------------------------------------------------------------
extern "C" void kernel_launch(void* const* d_in, const int* in_sizes, int n_in,
                              void* d_out, int out_size, void* d_ws, size_t ws_size,
                              hipStream_t stream) {
    const float* x   = (const float*)d_in[0];
    const int* ei    = (const int*)d_in[1];
    const int* batch = (const int*)d_in[3];
    const float* W0  = (const float*)d_in[4];
    const float* as0 = (const float*)d_in[5];
    const float* ad0 = (const float*)d_in[6];
    const float* b0  = (const float*)d_in[7];
    const float* W1  = (const float*)d_in[8];
    const float* as1 = (const float*)d_in[9];
    const float* ad1 = (const float*)d_in[10];
    const float* b1  = (const float*)d_in[11];
    const float* W2  = (const float*)d_in[12];
    const float* as2 = (const float*)d_in[13];
    const float* ad2 = (const float*)d_in[14];
    const float* b2  = (const float*)d_in[15];
    const float* Wr1 = (const float*)d_in[16];
    const float* br1 = (const float*)d_in[17];
    const float* Wr2 = (const float*)d_in[18];
    const float* br2 = (const float*)d_in[19];
    float* out = (float*)d_out;

    // workspace layout (halves unless noted); all sizes keep 16B alignment
    __half* h_buf = (__half*)d_ws;                          // NN*256 (25.6MB)
    __half* x_hi  = h_buf + (size_t)NN * 256;               // NN*128 (12.8MB)
    __half* x_lo  = x_hi + (size_t)NN * 128;                // NN*128 (12.8MB)
    // xb (NN*64) aliases the x region: x dead after gemm0 completes
    __half* xb_hi = x_hi;
    __half* xb_lo = x_lo;
    __half* w0ph  = x_lo + (size_t)NN * 128;                // 32768
    __half* w0pl  = w0ph + 32768;
    __half* w1ph  = w0pl + 32768;                           // 16384
    __half* w1pl  = w1ph + 16384;
    __half* w2ph  = w1pl + 16384;
    __half* w2pl  = w2ph + 16384;
    float*  al_s  = (float*)(w2pl + 16384);                 // NN*4
    float*  al_d  = al_s + (size_t)NN * 4;                  // NN*4
    float*  gmp   = al_d + (size_t)NN * 4;                  // GG*64
    float*  gap   = gmp + (size_t)GG * 64;                  // GG*64
    int*    deg   = (int*)(gap + (size_t)GG * 64);          // NN
    int*    csr   = deg + NN;                               // NN*CAP (12.8MB)

    hipMemsetAsync(deg, 0, NN * sizeof(int), stream);
    build_csr<<<(EE + 255) / 256, 256, 0, stream>>>(ei, deg, csr);

    // input conversions
    convert_x<<<(NN * FIN / 8 + 255) / 256, 256, 0, stream>>>(x, x_hi, x_lo, NN * FIN);
    convert_w<<<16, 256, 0, stream>>>(W0, w0ph, w0pl, 128);
    convert_w<<<8, 256, 0, stream>>>(W1, w1ph, w1pl, 64);
    convert_w<<<8, 256, 0, stream>>>(W2, w2ph, w2pl, 64);

    const int gemm_grid = (NN + 63) / 64;
    const int agg_grid  = (NN + 3) / 4;

    // layer 0
    gemm_mfma<FIN><<<gemm_grid, 256, 0, stream>>>(x_hi, x_lo, w0ph, w0pl, as0, ad0, h_buf, al_s, al_d);
    gat_aggregate<<<agg_grid, 256, 0, stream>>>(h_buf, al_s, al_d, deg, csr, b0, xb_hi, xb_lo);
    // layer 1
    gemm_mfma<CC><<<gemm_grid, 256, 0, stream>>>(xb_hi, xb_lo, w1ph, w1pl, as1, ad1, h_buf, al_s, al_d);
    gat_aggregate<<<agg_grid, 256, 0, stream>>>(h_buf, al_s, al_d, deg, csr, b1, xb_hi, xb_lo);
    // layer 2
    gemm_mfma<CC><<<gemm_grid, 256, 0, stream>>>(xb_hi, xb_lo, w2ph, w2pl, as2, ad2, h_buf, al_s, al_d);
    gat_aggregate<<<agg_grid, 256, 0, stream>>>(h_buf, al_s, al_d, deg, csr, b2, xb_hi, xb_lo);

    // readout
    readout<<<GG, 256, 0, stream>>>(xb_hi, batch, gmp, gap);
    mlp_readout<<<GG, 64, 0, stream>>>(gmp, gap, Wr1, br1, Wr2, br2, out);
}

// Round 12
// 478.291 us; speedup vs baseline: 1.4271x; 1.0418x over previous
//
#include <hip/hip_runtime.h>
#include <hip/hip_bf16.h>
#include <hip/hip_fp16.h>

// Problem constants (fixed by the reference setup)
#define NN   50000
#define EE   800000
#define FIN  128
#define CC   64
#define HH   4
#define GG   512
#define CAP  64          // per-node CSR capacity (Poisson(16) in-degree; P(>64) ~ 2e-18)

typedef _Float16 f16x8 __attribute__((ext_vector_type(8)));
typedef float    f32x4 __attribute__((ext_vector_type(4)));

__device__ __forceinline__ float leaky02(float x) { return x >= 0.f ? x : 0.2f * x; }
__device__ __forceinline__ float leaky01(float x) { return x >= 0.f ? x : 0.01f * x; }

// ---------------------------------------------------------------------------
// CSR build: histogram placement with fixed capacity. Self-loops implicit.
// ---------------------------------------------------------------------------
__global__ __launch_bounds__(256) void build_csr(const int* __restrict__ ei,
                                                 int* __restrict__ deg,
                                                 int* __restrict__ csr) {
    int e = blockIdx.x * 256 + threadIdx.x;
    if (e >= EE) return;
    int s = ei[e];
    int d = ei[EE + e];
    if ((unsigned)d >= NN || (unsigned)s >= NN) return;
    int pos = atomicAdd(&deg[d], 1);
    if (pos < CAP) csr[d * CAP + pos] = s;
}

// ---------------------------------------------------------------------------
// Pack all three W into MFMA B-fragment order (hi/lo fp16), one dispatch.
// Wp[((kc*16 + c)*64 + lane)*8 + j] = W[kc*32 + (lane>>4)*8 + j][c*16 + (lane&15)]
// Blocks 0..15 -> W0 (K=128), 16..23 -> W1, 24..31 -> W2 (K=64).
// ---------------------------------------------------------------------------
__global__ __launch_bounds__(256) void convert_w3(const float* __restrict__ W0,
                                                  const float* __restrict__ W1,
                                                  const float* __restrict__ W2,
                                                  __half* __restrict__ w0ph, __half* __restrict__ w0pl,
                                                  __half* __restrict__ w1ph, __half* __restrict__ w1pl,
                                                  __half* __restrict__ w2ph, __half* __restrict__ w2pl) {
    const float* W;
    __half *wph, *wpl;
    int id;
    if (blockIdx.x < 16)      { W = W0; wph = w0ph; wpl = w0pl; id = blockIdx.x * 256 + threadIdx.x; }
    else if (blockIdx.x < 24) { W = W1; wph = w1ph; wpl = w1pl; id = (blockIdx.x - 16) * 256 + threadIdx.x; }
    else                      { W = W2; wph = w2ph; wpl = w2pl; id = (blockIdx.x - 24) * 256 + threadIdx.x; }
    int lane = id & 63;
    int c    = (id >> 6) & 15;
    int kc   = id >> 10;
    int kbase = kc * 32 + (lane >> 4) * 8;
    int col   = c * 16 + (lane & 15);
    __half hi[8], lo[8];
#pragma unroll
    for (int j = 0; j < 8; ++j) {
        float v = W[(size_t)(kbase + j) * 256 + col];
        hi[j] = __float2half_rn(v);
        lo[j] = __float2half_rn(v - __half2float(hi[j]));
    }
    *(uint4*)(wph + (size_t)id * 8) = *(uint4*)hi;
    *(uint4*)(wpl + (size_t)id * 8) = *(uint4*)lo;
}

// ---------------------------------------------------------------------------
// MFMA GEMM: h = X @ W. Block 256 = 4 waves; wave owns 16 rows x 256 cols.
// XF32=true: X fp32, in-register Markidis split, 3 MFMAs/tile (fp32 quality).
// XF32=false: X fp16 (hi only), 2 MFMAs/tile (exact W via hi/lo).
// A frag: row=lane&15, k=(lane>>4)*8+j. C frag: col=lane&15, row=(lane>>4)*4+r.
// Epilogue: fused al_s/al_d; h staged through per-wave XOR-swizzled LDS so
// global stores are coalesced 16B.
// ---------------------------------------------------------------------------
template <int K, bool XF32>
__global__ __launch_bounds__(256) void gemm_mfma(const void* __restrict__ xin,
                                                 const __half* __restrict__ wph,
                                                 const __half* __restrict__ wpl,
                                                 const float* __restrict__ a_src,
                                                 const float* __restrict__ a_dst,
                                                 __half* __restrict__ h_out,
                                                 float* __restrict__ al_s,
                                                 float* __restrict__ al_d) {
    __shared__ __half hst[4][16 * 256];            // 8KB per wave
    const int t    = threadIdx.x;
    const int w    = t >> 6;
    const int lane = t & 63;
    const int r0   = blockIdx.x * 64 + w * 16;
    const int colL = lane & 15;
    const int rowg = lane >> 4;
    int arow = r0 + colL;
    arow = arow < NN ? arow : NN - 1;              // clamp (stores guarded)
    const int koff = rowg * 8;

    f32x4 acc[16];
#pragma unroll
    for (int c = 0; c < 16; ++c) acc[c] = (f32x4){0.f, 0.f, 0.f, 0.f};

    for (int kc = 0; kc < K / 32; ++kc) {
        f16x8 ah, al;
        if (XF32) {
            const float* xf = (const float*)xin;
            float v[8];
            *(float4*)&v[0] = *(const float4*)(xf + (size_t)arow * K + kc * 32 + koff);
            *(float4*)&v[4] = *(const float4*)(xf + (size_t)arow * K + kc * 32 + koff + 4);
#pragma unroll
            for (int j = 0; j < 8; ++j) {
                float hi = (float)(_Float16)v[j];
                ah[j] = (_Float16)v[j];
                al[j] = (_Float16)(v[j] - hi);
            }
        } else {
            const __half* xh = (const __half*)xin;
            ah = *(const f16x8*)(xh + (size_t)arow * K + kc * 32 + koff);
        }
        const __half* bbase_h = wph + ((size_t)(kc * 16) * 64 + lane) * 8;
        const __half* bbase_l = wpl + ((size_t)(kc * 16) * 64 + lane) * 8;
#pragma unroll
        for (int c = 0; c < 16; ++c) {
            f16x8 bh = *(const f16x8*)(bbase_h + c * 512);
            f16x8 bl = *(const f16x8*)(bbase_l + c * 512);
            acc[c] = __builtin_amdgcn_mfma_f32_16x16x32_f16(ah, bh, acc[c], 0, 0, 0);
            acc[c] = __builtin_amdgcn_mfma_f32_16x16x32_f16(ah, bl, acc[c], 0, 0, 0);
            if (XF32)
                acc[c] = __builtin_amdgcn_mfma_f32_16x16x32_f16(al, bh, acc[c], 0, 0, 0);
        }
    }

    // ---- fused attention logits from exact fp32 accs ----
    float aps[4][4], apd[4][4];
#pragma unroll
    for (int r = 0; r < 4; ++r)
#pragma unroll
        for (int h = 0; h < 4; ++h) { aps[r][h] = 0.f; apd[r][h] = 0.f; }
#pragma unroll
    for (int c = 0; c < 16; ++c) {
        const int col = c * 16 + colL;
        const float as = a_src[col];
        const float ad = a_dst[col];
        const int hh = c >> 2;
#pragma unroll
        for (int r = 0; r < 4; ++r) {
            aps[r][hh] = fmaf(acc[c][r], as, aps[r][hh]);
            apd[r][hh] = fmaf(acc[c][r], ad, apd[r][hh]);
        }
    }
#pragma unroll
    for (int r = 0; r < 4; ++r)
#pragma unroll
        for (int h = 0; h < 4; ++h) {
            float s = aps[r][h], d = apd[r][h];
#pragma unroll
            for (int off = 1; off <= 8; off <<= 1) {
                s += __shfl_xor(s, off, 64);
                d += __shfl_xor(d, off, 64);
            }
            aps[r][h] = s; apd[r][h] = d;
        }
    if (colL == 0) {
#pragma unroll
        for (int r = 0; r < 4; ++r) {
            const int row = r0 + rowg * 4 + r;
            if (row < NN) {
#pragma unroll
                for (int h = 0; h < 4; ++h) {
                    al_s[(size_t)row * 4 + h] = aps[r][h];
                    al_d[(size_t)row * 4 + h] = apd[r][h];
                }
            }
        }
    }

    // ---- h store via per-wave LDS (XOR-swizzled 16B chunks) ----
    __half* my = hst[w];
#pragma unroll
    for (int c = 0; c < 16; ++c) {
        const int c16 = c * 2 + (colL >> 3);       // 16B chunk id 0..31
#pragma unroll
        for (int r = 0; r < 4; ++r) {
            const int rl = rowg * 4 + r;           // row_local 0..15
            my[rl * 256 + ((c16 ^ rl) * 8) + (colL & 7)] = __float2half_rn(acc[c][r]);
        }
    }
    // same-wave LDS write->read: compiler inserts lgkmcnt wait; no barrier needed
    {
        const int rl = lane >> 2;                  // 0..15
        const int row = r0 + rl;
        if (row < NN) {
#pragma unroll
            for (int j = 0; j < 8; ++j) {
                const int chunk = (lane & 3) * 8 + j;   // 0..31
                uint4 v = *(const uint4*)&my[rl * 256 + ((chunk ^ rl) * 8)];
                *(uint4*)(h_out + (size_t)row * 256 + chunk * 8) = v;
            }
        }
    }
}

// ---------------------------------------------------------------------------
// Per-dst segment softmax + aggregation. One wave per dst node. Softmax fp32;
// coef in LDS as dup'd half2; two virtual rows per iter (wave halves); fp16
// pk-fma accumulate; 32-bit byte offsets for the gather. Output fp16 (hi only).
// ---------------------------------------------------------------------------
struct Half8 { __half2 h[4]; };

__global__ __launch_bounds__(256) void gat_aggregate(const __half* __restrict__ h_buf,
                                                     const float* __restrict__ al_s,
                                                     const float* __restrict__ al_d,
                                                     const int* __restrict__ deg,
                                                     const int* __restrict__ csr,
                                                     const float* __restrict__ bias,
                                                     __half* __restrict__ xb) {
    __shared__ __align__(16) __half2 els[4][66][4];
    const int w    = threadIdx.x >> 6;
    const int lane = threadIdx.x & 63;
    const int n    = blockIdx.x * 4 + w;
    const int d = min(deg[n], CAP);

    float4 ad4 = *(const float4*)(al_d + (size_t)n * 4);
    float4 as4 = *(const float4*)(al_s + (size_t)n * 4);
    const float* adp = (const float*)&ad4;
    const float* asp = (const float*)&as4;

    float aself[4];
#pragma unroll
    for (int h = 0; h < 4; ++h) aself[h] = leaky02(asp[h] + adp[h]);

    int s_lane = 0;
    float a_lane[4];
    if (lane < d) {
        s_lane = csr[(size_t)n * CAP + lane];
        float4 s4 = *(const float4*)(al_s + (size_t)s_lane * 4);
        const float* sp = (const float*)&s4;
#pragma unroll
        for (int h = 0; h < 4; ++h) a_lane[h] = leaky02(sp[h] + adp[h]);
    } else {
#pragma unroll
        for (int h = 0; h < 4; ++h) a_lane[h] = -INFINITY;
    }

    float mx[4];
#pragma unroll
    for (int h = 0; h < 4; ++h) {
        mx[h] = fmaxf(aself[h], a_lane[h]);
#pragma unroll
        for (int off = 32; off; off >>= 1) mx[h] = fmaxf(mx[h], __shfl_xor(mx[h], off, 64));
    }

    float e[4], sm[4];
#pragma unroll
    for (int h = 0; h < 4; ++h) {
        e[h] = (lane < d) ? expf(a_lane[h] - mx[h]) : 0.f;
        sm[h] = e[h];
#pragma unroll
        for (int off = 32; off; off >>= 1) sm[h] += __shfl_xor(sm[h], off, 64);
    }
    float eself[4], inv[4];
#pragma unroll
    for (int h = 0; h < 4; ++h) {
        eself[h] = expf(aself[h] - mx[h]);
        inv[h] = 1.f / (sm[h] + eself[h] + 1e-16f);
    }
    if (lane < d) {
#pragma unroll
        for (int h = 0; h < 4; ++h) {
            float c = e[h] * inv[h];
            els[w][lane + 1][h] = __floats2half2_rn(c, c);
        }
    }
    if (lane == 0) {
#pragma unroll
        for (int h = 0; h < 4; ++h) {
            float c = eself[h] * inv[h];
            els[w][0][h] = __floats2half2_rn(c, c);
        }
    }

    const int q    = lane >> 5;
    const int m    = lane & 31;
    const int head = m >> 3;
    const char* __restrict__ hb = (const char*)h_buf + m * 16;   // 8 halves = 16B

    __half2 z = __floats2half2_rn(0.f, 0.f);
    __half2 acc0 = z, acc1 = z, acc2 = z, acc3 = z;
    const int count = d + 1;
    for (int t2 = 0; 2 * t2 < count; ++t2) {
        int v = 2 * t2 + q;
        int vi = v > 0 ? v - 1 : 0;
        int s = __shfl(s_lane, vi, 64);
        s = v == 0 ? n : s;
        if (v < count) {
            __half2 c2 = els[w][v][head];
            Half8 r = *(const Half8*)(hb + (size_t)((unsigned)s << 9));
            acc0 = __hfma2(r.h[0], c2, acc0);
            acc1 = __hfma2(r.h[1], c2, acc1);
            acc2 = __hfma2(r.h[2], c2, acc2);
            acc3 = __hfma2(r.h[3], c2, acc3);
        }
    }

    int i0 = __shfl_xor(*(int*)&acc0, 32, 64);
    int i1 = __shfl_xor(*(int*)&acc1, 32, 64);
    int i2 = __shfl_xor(*(int*)&acc2, 32, 64);
    int i3 = __shfl_xor(*(int*)&acc3, 32, 64);
    acc0 = __hadd2(acc0, *(__half2*)&i0);
    acc1 = __hadd2(acc1, *(__half2*)&i1);
    acc2 = __hadd2(acc2, *(__half2*)&i2);
    acc3 = __hadd2(acc3, *(__half2*)&i3);

    float ch[8];
    float2 f;
    f = __half22float2(acc0); ch[0] = f.x; ch[1] = f.y;
    f = __half22float2(acc1); ch[2] = f.x; ch[3] = f.y;
    f = __half22float2(acc2); ch[4] = f.x; ch[5] = f.y;
    f = __half22float2(acc3); ch[6] = f.x; ch[7] = f.y;
#pragma unroll
    for (int k = 0; k < 8; ++k) {
        ch[k] += __shfl_xor(ch[k], 8, 64);
        ch[k] += __shfl_xor(ch[k], 16, 64);
    }
    if (lane < 8) {
        __align__(16) __half h8[8];
#pragma unroll
        for (int k = 0; k < 8; ++k)
            h8[k] = __float2half_rn(leaky01(ch[k] * 0.25f + bias[lane * 8 + k]));
        *(uint4*)(xb + (size_t)n * 64 + lane * 8) = *(uint4*)h8;
    }
}

// ---------------------------------------------------------------------------
// Readout: one block per graph g; batch sorted -> binary search. Reads fp16.
// ---------------------------------------------------------------------------
__global__ __launch_bounds__(256) void readout(const __half* __restrict__ x,
                                               const int* __restrict__ batch,
                                               float* __restrict__ gmp,
                                               float* __restrict__ gap) {
    int g = blockIdx.x;
    int a = 0, b = NN;
    while (a < b) { int m = (a + b) >> 1; if (batch[m] < g) a = m + 1; else b = m; }
    int lo = a;
    a = lo; b = NN;
    while (a < b) { int m = (a + b) >> 1; if (batch[m] < g + 1) a = m + 1; else b = m; }
    int hi = a;

    int t = threadIdx.x, c = t & 63, s = t >> 6;
    float mx = -INFINITY, sm = 0.f;
    for (int n = lo + s; n < hi; n += 4) {
        float v = __half2float(x[(size_t)n * 64 + c]);
        mx = fmaxf(mx, v);
        sm += v;
    }
    __shared__ float smx[256], ssm[256];
    smx[t] = mx; ssm[t] = sm;
    __syncthreads();
    if (t < 64) {
        mx = fmaxf(fmaxf(smx[t], smx[t + 64]), fmaxf(smx[t + 128], smx[t + 192]));
        sm = ssm[t] + ssm[t + 64] + ssm[t + 128] + ssm[t + 192];
        int cnt = hi - lo;
        gmp[g * 64 + t] = mx;
        gap[g * 64 + t] = sm / fmaxf((float)cnt, 1.0f);
    }
}

// ---------------------------------------------------------------------------
// Final MLP: one wave per graph.
// ---------------------------------------------------------------------------
__global__ __launch_bounds__(64) void mlp_readout(const float* __restrict__ gmp,
                                                  const float* __restrict__ gap,
                                                  const float* __restrict__ Wr1,
                                                  const float* __restrict__ br1,
                                                  const float* __restrict__ Wr2,
                                                  const float* __restrict__ br2,
                                                  float* __restrict__ out) {
    int g = blockIdx.x;
    int j = threadIdx.x;
    double acc = (double)br1[j];
    for (int i = 0; i < 64; ++i) acc += (double)gmp[g * 64 + i] * (double)Wr1[i * 64 + j];
    for (int i = 0; i < 64; ++i) acc += (double)gap[g * 64 + i] * (double)Wr1[(64 + i) * 64 + j];
    float v = (float)acc;
    v = v >= 0.f ? v : 0.01f * v;
    double tv = (double)v * (double)Wr2[j];
#pragma unroll
    for (int off = 32; off; off >>= 1) tv += __shfl_xor(tv, off, 64);
    if (j == 0) out[g] = (float)(tv + (double)br2[0]);
}

// ---------------------------------------------------------------------------
extern "C" void kernel_launch(void* const* d_in, const int* in_sizes, int n_in,
                              void* d_out, int out_size, void* d_ws, size_t ws_size,
                              hipStream_t stream) {
    const float* x   = (const float*)d_in[0];
    const int* ei    = (const int*)d_in[1];
    const int* batch = (const int*)d_in[3];
    const float* W0  = (const float*)d_in[4];
    const float* as0 = (const float*)d_in[5];
    const float* ad0 = (const float*)d_in[6];
    const float* b0  = (const float*)d_in[7];
    const float* W1  = (const float*)d_in[8];
    const float* as1 = (const float*)d_in[9];
    const float* ad1 = (const float*)d_in[10];
    const float* b1  = (const float*)d_in[11];
    const float* W2  = (const float*)d_in[12];
    const float* as2 = (const float*)d_in[13];
    const float* ad2 = (const float*)d_in[14];
    const float* b2  = (const float*)d_in[15];
    const float* Wr1 = (const float*)d_in[16];
    const float* br1 = (const float*)d_in[17];
    const float* Wr2 = (const float*)d_in[18];
    const float* br2 = (const float*)d_in[19];
    float* out = (float*)d_out;

    // workspace layout (halves unless noted)
    __half* h_buf = (__half*)d_ws;                          // NN*256 (25.6MB)
    __half* xb    = h_buf + (size_t)NN * 256;               // NN*64  (6.4MB)
    __half* w0ph  = xb + (size_t)NN * 64;                   // 32768
    __half* w0pl  = w0ph + 32768;
    __half* w1ph  = w0pl + 32768;                           // 16384
    __half* w1pl  = w1ph + 16384;
    __half* w2ph  = w1pl + 16384;
    __half* w2pl  = w2ph + 16384;
    float*  al_s  = (float*)(w2pl + 16384);                 // NN*4
    float*  al_d  = al_s + (size_t)NN * 4;                  // NN*4
    float*  gmp   = al_d + (size_t)NN * 4;                  // GG*64
    float*  gap   = gmp + (size_t)GG * 64;                  // GG*64
    int*    deg   = (int*)(gap + (size_t)GG * 64);          // NN
    int*    csr   = deg + NN;                               // NN*CAP (12.8MB)

    hipMemsetAsync(deg, 0, NN * sizeof(int), stream);
    build_csr<<<(EE + 255) / 256, 256, 0, stream>>>(ei, deg, csr);
    convert_w3<<<32, 256, 0, stream>>>(W0, W1, W2, w0ph, w0pl, w1ph, w1pl, w2ph, w2pl);

    const int gemm_grid = (NN + 63) / 64;
    const int agg_grid  = (NN + 3) / 4;

    // layer 0 (fp32 x, Markidis 3-mul)
    gemm_mfma<FIN, true><<<gemm_grid, 256, 0, stream>>>(x, w0ph, w0pl, as0, ad0, h_buf, al_s, al_d);
    gat_aggregate<<<agg_grid, 256, 0, stream>>>(h_buf, al_s, al_d, deg, csr, b0, xb);
    // layer 1 (fp16 x, 2-mul)
    gemm_mfma<CC, false><<<gemm_grid, 256, 0, stream>>>(xb, w1ph, w1pl, as1, ad1, h_buf, al_s, al_d);
    gat_aggregate<<<agg_grid, 256, 0, stream>>>(h_buf, al_s, al_d, deg, csr, b1, xb);
    // layer 2
    gemm_mfma<CC, false><<<gemm_grid, 256, 0, stream>>>(xb, w2ph, w2pl, as2, ad2, h_buf, al_s, al_d);
    gat_aggregate<<<agg_grid, 256, 0, stream>>>(h_buf, al_s, al_d, deg, csr, b2, xb);

    // readout
    readout<<<GG, 256, 0, stream>>>(xb, batch, gmp, gap);
    mlp_readout<<<GG, 64, 0, stream>>>(gmp, gap, Wr1, br1, Wr2, br2, out);
}

// Round 14
// 467.620 us; speedup vs baseline: 1.4597x; 1.0228x over previous
//
#include <hip/hip_runtime.h>
#include <hip/hip_bf16.h>
#include <hip/hip_fp16.h>

// Problem constants (fixed by the reference setup)
#define NN   50000
#define EE   800000
#define FIN  128
#define CC   64
#define HH   4
#define GG   512
#define CAP  64          // per-node CSR capacity (Poisson(16) in-degree; P(>64) ~ 2e-18)
#define EBLK 1563        // ceil(EE / (256*2))

typedef _Float16 f16x8 __attribute__((ext_vector_type(8)));
typedef float    f32x4 __attribute__((ext_vector_type(4)));

__device__ __forceinline__ float leaky02(float x) { return x >= 0.f ? x : 0.2f * x; }
__device__ __forceinline__ float leaky01(float x) { return x >= 0.f ? x : 0.01f * x; }

// ---------------------------------------------------------------------------
// Fused: CSR build (uint16 entries, 2 edges/thread) + W fragment packing.
// Blocks [0,EBLK): edges. Blocks [EBLK, EBLK+32): pack W0/W1/W2 hi/lo.
// ---------------------------------------------------------------------------
__global__ __launch_bounds__(256) void build_csr_w(const int* __restrict__ ei,
                                                   int* __restrict__ deg,
                                                   unsigned short* __restrict__ csr,
                                                   const float* __restrict__ W0,
                                                   const float* __restrict__ W1,
                                                   const float* __restrict__ W2,
                                                   __half* __restrict__ w0ph, __half* __restrict__ w0pl,
                                                   __half* __restrict__ w1ph, __half* __restrict__ w1pl,
                                                   __half* __restrict__ w2ph, __half* __restrict__ w2pl) {
    const int b = blockIdx.x;
    if (b < EBLK) {
        int e = (b * 256 + threadIdx.x) * 2;
        if (e >= EE) return;
        int2 ss = *(const int2*)(ei + e);        // sources e, e+1
        int2 dd = *(const int2*)(ei + EE + e);   // dsts    e, e+1
        if ((unsigned)dd.x < NN && (unsigned)ss.x < NN) {
            int pos = atomicAdd(&deg[dd.x], 1);
            if (pos < CAP) csr[dd.x * CAP + pos] = (unsigned short)ss.x;
        }
        if ((unsigned)dd.y < NN && (unsigned)ss.y < NN) {
            int pos = atomicAdd(&deg[dd.y], 1);
            if (pos < CAP) csr[dd.y * CAP + pos] = (unsigned short)ss.y;
        }
        return;
    }
    // ---- W packing ----
    const int wb = b - EBLK;
    const float* W;
    __half *wph, *wpl;
    int id;
    if (wb < 16)      { W = W0; wph = w0ph; wpl = w0pl; id = wb * 256 + threadIdx.x; }
    else if (wb < 24) { W = W1; wph = w1ph; wpl = w1pl; id = (wb - 16) * 256 + threadIdx.x; }
    else              { W = W2; wph = w2ph; wpl = w2pl; id = (wb - 24) * 256 + threadIdx.x; }
    int lane = id & 63;
    int c    = (id >> 6) & 15;
    int kc   = id >> 10;
    int kbase = kc * 32 + (lane >> 4) * 8;
    int col   = c * 16 + (lane & 15);
    __half hi[8], lo[8];
#pragma unroll
    for (int j = 0; j < 8; ++j) {
        float v = W[(size_t)(kbase + j) * 256 + col];
        hi[j] = __float2half_rn(v);
        lo[j] = __float2half_rn(v - __half2float(hi[j]));
    }
    *(uint4*)(wph + (size_t)id * 8) = *(uint4*)hi;
    *(uint4*)(wpl + (size_t)id * 8) = *(uint4*)lo;
}

// ---------------------------------------------------------------------------
// MFMA GEMM: h = X @ W. Block 256 = 4 waves; wave owns 16 rows x 256 cols.
// XF32=true: X fp32, in-register Markidis split, 3 MFMAs/tile (fp32 quality).
// XF32=false: X fp16 (hi only), 2 MFMAs/tile (exact W via hi/lo).
// A frag: row=lane&15, k=(lane>>4)*8+j. C frag: col=lane&15, row=(lane>>4)*4+r.
// Epilogue: fused al_s/al_d; h staged through per-wave XOR-swizzled LDS so
// global stores are coalesced 16B.
// ---------------------------------------------------------------------------
template <int K, bool XF32>
__global__ __launch_bounds__(256) void gemm_mfma(const void* __restrict__ xin,
                                                 const __half* __restrict__ wph,
                                                 const __half* __restrict__ wpl,
                                                 const float* __restrict__ a_src,
                                                 const float* __restrict__ a_dst,
                                                 __half* __restrict__ h_out,
                                                 float* __restrict__ al_s,
                                                 float* __restrict__ al_d) {
    __shared__ __half hst[4][16 * 256];            // 8KB per wave
    const int t    = threadIdx.x;
    const int w    = t >> 6;
    const int lane = t & 63;
    const int r0   = blockIdx.x * 64 + w * 16;
    const int colL = lane & 15;
    const int rowg = lane >> 4;
    int arow = r0 + colL;
    arow = arow < NN ? arow : NN - 1;              // clamp (stores guarded)
    const int koff = rowg * 8;

    f32x4 acc[16];
#pragma unroll
    for (int c = 0; c < 16; ++c) acc[c] = (f32x4){0.f, 0.f, 0.f, 0.f};

    for (int kc = 0; kc < K / 32; ++kc) {
        f16x8 ah, al;
        if (XF32) {
            const float* xf = (const float*)xin;
            float v[8];
            *(float4*)&v[0] = *(const float4*)(xf + (size_t)arow * K + kc * 32 + koff);
            *(float4*)&v[4] = *(const float4*)(xf + (size_t)arow * K + kc * 32 + koff + 4);
#pragma unroll
            for (int j = 0; j < 8; ++j) {
                float hi = (float)(_Float16)v[j];
                ah[j] = (_Float16)v[j];
                al[j] = (_Float16)(v[j] - hi);
            }
        } else {
            const __half* xh = (const __half*)xin;
            ah = *(const f16x8*)(xh + (size_t)arow * K + kc * 32 + koff);
        }
        const __half* bbase_h = wph + ((size_t)(kc * 16) * 64 + lane) * 8;
        const __half* bbase_l = wpl + ((size_t)(kc * 16) * 64 + lane) * 8;
#pragma unroll
        for (int c = 0; c < 16; ++c) {
            f16x8 bh = *(const f16x8*)(bbase_h + c * 512);
            f16x8 bl = *(const f16x8*)(bbase_l + c * 512);
            acc[c] = __builtin_amdgcn_mfma_f32_16x16x32_f16(ah, bh, acc[c], 0, 0, 0);
            acc[c] = __builtin_amdgcn_mfma_f32_16x16x32_f16(ah, bl, acc[c], 0, 0, 0);
            if (XF32)
                acc[c] = __builtin_amdgcn_mfma_f32_16x16x32_f16(al, bh, acc[c], 0, 0, 0);
        }
    }

    // ---- fused attention logits from exact fp32 accs ----
    float aps[4][4], apd[4][4];
#pragma unroll
    for (int r = 0; r < 4; ++r)
#pragma unroll
        for (int h = 0; h < 4; ++h) { aps[r][h] = 0.f; apd[r][h] = 0.f; }
#pragma unroll
    for (int c = 0; c < 16; ++c) {
        const int col = c * 16 + colL;
        const float as = a_src[col];
        const float ad = a_dst[col];
        const int hh = c >> 2;
#pragma unroll
        for (int r = 0; r < 4; ++r) {
            aps[r][hh] = fmaf(acc[c][r], as, aps[r][hh]);
            apd[r][hh] = fmaf(acc[c][r], ad, apd[r][hh]);
        }
    }
#pragma unroll
    for (int r = 0; r < 4; ++r)
#pragma unroll
        for (int h = 0; h < 4; ++h) {
            float s = aps[r][h], d = apd[r][h];
#pragma unroll
            for (int off = 1; off <= 8; off <<= 1) {
                s += __shfl_xor(s, off, 64);
                d += __shfl_xor(d, off, 64);
            }
            aps[r][h] = s; apd[r][h] = d;
        }
    if (colL == 0) {
#pragma unroll
        for (int r = 0; r < 4; ++r) {
            const int row = r0 + rowg * 4 + r;
            if (row < NN) {
#pragma unroll
                for (int h = 0; h < 4; ++h) {
                    al_s[(size_t)row * 4 + h] = aps[r][h];
                    al_d[(size_t)row * 4 + h] = apd[r][h];
                }
            }
        }
    }

    // ---- h store via per-wave LDS (XOR-swizzled 16B chunks) ----
    __half* my = hst[w];
#pragma unroll
    for (int c = 0; c < 16; ++c) {
        const int c16 = c * 2 + (colL >> 3);       // 16B chunk id 0..31
#pragma unroll
        for (int r = 0; r < 4; ++r) {
            const int rl = rowg * 4 + r;           // row_local 0..15
            my[rl * 256 + ((c16 ^ rl) * 8) + (colL & 7)] = __float2half_rn(acc[c][r]);
        }
    }
    // same-wave LDS write->read: compiler inserts lgkmcnt wait; no barrier needed
    {
        const int rl = lane >> 2;                  // 0..15
        const int row = r0 + rl;
        if (row < NN) {
#pragma unroll
            for (int j = 0; j < 8; ++j) {
                const int chunk = (lane & 3) * 8 + j;   // 0..31
                uint4 v = *(const uint4*)&my[rl * 256 + ((chunk ^ rl) * 8)];
                *(uint4*)(h_out + (size_t)row * 256 + chunk * 8) = v;
            }
        }
    }
}

// ---------------------------------------------------------------------------
// Per-dst segment softmax + aggregation. One wave per dst node. Softmax fp32;
// coef in LDS as dup'd half2; two virtual rows per iter (wave halves); fp16
// pk-fma accumulate; 32-bit byte offsets for the gather. Output fp16.
// ---------------------------------------------------------------------------
struct Half8 { __half2 h[4]; };

__global__ __launch_bounds__(256) void gat_aggregate(const __half* __restrict__ h_buf,
                                                     const float* __restrict__ al_s,
                                                     const float* __restrict__ al_d,
                                                     const int* __restrict__ deg,
                                                     const unsigned short* __restrict__ csr,
                                                     const float* __restrict__ bias,
                                                     __half* __restrict__ xb) {
    __shared__ __align__(16) __half2 els[4][66][4];
    const int w    = threadIdx.x >> 6;
    const int lane = threadIdx.x & 63;
    const int n    = blockIdx.x * 4 + w;
    const int d = min(deg[n], CAP);

    float4 ad4 = *(const float4*)(al_d + (size_t)n * 4);
    float4 as4 = *(const float4*)(al_s + (size_t)n * 4);
    const float* adp = (const float*)&ad4;
    const float* asp = (const float*)&as4;

    float aself[4];
#pragma unroll
    for (int h = 0; h < 4; ++h) aself[h] = leaky02(asp[h] + adp[h]);

    int s_lane = 0;
    float a_lane[4];
    if (lane < d) {
        s_lane = csr[n * CAP + lane];
        float4 s4 = *(const float4*)(al_s + (size_t)s_lane * 4);
        const float* sp = (const float*)&s4;
#pragma unroll
        for (int h = 0; h < 4; ++h) a_lane[h] = leaky02(sp[h] + adp[h]);
    } else {
#pragma unroll
        for (int h = 0; h < 4; ++h) a_lane[h] = -INFINITY;
    }

    float mx[4];
#pragma unroll
    for (int h = 0; h < 4; ++h) {
        mx[h] = fmaxf(aself[h], a_lane[h]);
#pragma unroll
        for (int off = 32; off; off >>= 1) mx[h] = fmaxf(mx[h], __shfl_xor(mx[h], off, 64));
    }

    float e[4], sm[4];
#pragma unroll
    for (int h = 0; h < 4; ++h) {
        e[h] = (lane < d) ? expf(a_lane[h] - mx[h]) : 0.f;
        sm[h] = e[h];
#pragma unroll
        for (int off = 32; off; off >>= 1) sm[h] += __shfl_xor(sm[h], off, 64);
    }
    float eself[4], inv[4];
#pragma unroll
    for (int h = 0; h < 4; ++h) {
        eself[h] = expf(aself[h] - mx[h]);
        inv[h] = 1.f / (sm[h] + eself[h] + 1e-16f);
    }
    if (lane < d) {
#pragma unroll
        for (int h = 0; h < 4; ++h) {
            float c = e[h] * inv[h];
            els[w][lane + 1][h] = __floats2half2_rn(c, c);
        }
    }
    if (lane == 0) {
#pragma unroll
        for (int h = 0; h < 4; ++h) {
            float c = eself[h] * inv[h];
            els[w][0][h] = __floats2half2_rn(c, c);
        }
    }

    const int q    = lane >> 5;
    const int m    = lane & 31;
    const int head = m >> 3;
    const char* __restrict__ hb = (const char*)h_buf + m * 16;   // 8 halves = 16B

    __half2 z = __floats2half2_rn(0.f, 0.f);
    __half2 acc0 = z, acc1 = z, acc2 = z, acc3 = z;
    const int count = d + 1;
    for (int t2 = 0; 2 * t2 < count; ++t2) {
        int v = 2 * t2 + q;
        int vi = v > 0 ? v - 1 : 0;
        int s = __shfl(s_lane, vi, 64);
        s = v == 0 ? n : s;
        if (v < count) {
            __half2 c2 = els[w][v][head];
            Half8 r = *(const Half8*)(hb + (size_t)((unsigned)s << 9));
            acc0 = __hfma2(r.h[0], c2, acc0);
            acc1 = __hfma2(r.h[1], c2, acc1);
            acc2 = __hfma2(r.h[2], c2, acc2);
            acc3 = __hfma2(r.h[3], c2, acc3);
        }
    }

    int i0 = __shfl_xor(*(int*)&acc0, 32, 64);
    int i1 = __shfl_xor(*(int*)&acc1, 32, 64);
    int i2 = __shfl_xor(*(int*)&acc2, 32, 64);
    int i3 = __shfl_xor(*(int*)&acc3, 32, 64);
    acc0 = __hadd2(acc0, *(__half2*)&i0);
    acc1 = __hadd2(acc1, *(__half2*)&i1);
    acc2 = __hadd2(acc2, *(__half2*)&i2);
    acc3 = __hadd2(acc3, *(__half2*)&i3);

    float ch[8];
    float2 f;
    f = __half22float2(acc0); ch[0] = f.x; ch[1] = f.y;
    f = __half22float2(acc1); ch[2] = f.x; ch[3] = f.y;
    f = __half22float2(acc2); ch[4] = f.x; ch[5] = f.y;
    f = __half22float2(acc3); ch[6] = f.x; ch[7] = f.y;
#pragma unroll
    for (int k = 0; k < 8; ++k) {
        ch[k] += __shfl_xor(ch[k], 8, 64);
        ch[k] += __shfl_xor(ch[k], 16, 64);
    }
    if (lane < 8) {
        __align__(16) __half h8[8];
#pragma unroll
        for (int k = 0; k < 8; ++k)
            h8[k] = __float2half_rn(leaky01(ch[k] * 0.25f + bias[lane * 8 + k]));
        *(uint4*)(xb + (size_t)n * 64 + lane * 8) = *(uint4*)h8;
    }
}

// ---------------------------------------------------------------------------
// Fused readout + MLP: one block per graph. Per-channel max/mean -> smem
// hid[128] -> leaky(hid@Wr1+br1) -> @Wr2+br2 -> out[g].
// ---------------------------------------------------------------------------
__global__ __launch_bounds__(256) void readout_mlp(const __half* __restrict__ x,
                                                   const int* __restrict__ batch,
                                                   const float* __restrict__ Wr1,
                                                   const float* __restrict__ br1,
                                                   const float* __restrict__ Wr2,
                                                   const float* __restrict__ br2,
                                                   float* __restrict__ out) {
    int g = blockIdx.x;
    int a = 0, b = NN;
    while (a < b) { int m = (a + b) >> 1; if (batch[m] < g) a = m + 1; else b = m; }
    int lo = a;
    a = lo; b = NN;
    while (a < b) { int m = (a + b) >> 1; if (batch[m] < g + 1) a = m + 1; else b = m; }
    int hi = a;

    int t = threadIdx.x, c = t & 63, s = t >> 6;
    float mx = -INFINITY, sm = 0.f;
    for (int n = lo + s; n < hi; n += 4) {
        float v = __half2float(x[(size_t)n * 64 + c]);
        mx = fmaxf(mx, v);
        sm += v;
    }
    __shared__ float smx[256], ssm[256];
    __shared__ float hid[128];
    __shared__ float part[4][64];
    smx[t] = mx; ssm[t] = sm;
    __syncthreads();
    if (t < 64) {
        mx = fmaxf(fmaxf(smx[t], smx[t + 64]), fmaxf(smx[t + 128], smx[t + 192]));
        sm = ssm[t] + ssm[t + 64] + ssm[t + 128] + ssm[t + 192];
        int cnt = hi - lo;
        hid[t] = mx;
        hid[64 + t] = sm / fmaxf((float)cnt, 1.0f);
    }
    __syncthreads();
    // hidden layer: thread t computes partial of hidden j over inputs q*32..q*32+31
    {
        int j = t & 63, q = t >> 6;
        float p = 0.f;
#pragma unroll
        for (int i = 0; i < 32; ++i)
            p = fmaf(hid[q * 32 + i], Wr1[(q * 32 + i) * 64 + j], p);
        part[q][j] = p;
    }
    __syncthreads();
    if (t < 64) {
        float v = br1[t] + ((part[0][t] + part[1][t]) + (part[2][t] + part[3][t]));
        v = leaky01(v);
        float tv = v * Wr2[t];
#pragma unroll
        for (int off = 32; off; off >>= 1) tv += __shfl_xor(tv, off, 64);
        if (t == 0) out[g] = tv + br2[0];
    }
}

// ---------------------------------------------------------------------------
extern "C" void kernel_launch(void* const* d_in, const int* in_sizes, int n_in,
                              void* d_out, int out_size, void* d_ws, size_t ws_size,
                              hipStream_t stream) {
    const float* x   = (const float*)d_in[0];
    const int* ei    = (const int*)d_in[1];
    const int* batch = (const int*)d_in[3];
    const float* W0  = (const float*)d_in[4];
    const float* as0 = (const float*)d_in[5];
    const float* ad0 = (const float*)d_in[6];
    const float* b0  = (const float*)d_in[7];
    const float* W1  = (const float*)d_in[8];
    const float* as1 = (const float*)d_in[9];
    const float* ad1 = (const float*)d_in[10];
    const float* b1  = (const float*)d_in[11];
    const float* W2  = (const float*)d_in[12];
    const float* as2 = (const float*)d_in[13];
    const float* ad2 = (const float*)d_in[14];
    const float* b2  = (const float*)d_in[15];
    const float* Wr1 = (const float*)d_in[16];
    const float* br1 = (const float*)d_in[17];
    const float* Wr2 = (const float*)d_in[18];
    const float* br2 = (const float*)d_in[19];
    float* out = (float*)d_out;

    // workspace layout (halves unless noted)
    __half* h_buf = (__half*)d_ws;                          // NN*256 (25.6MB)
    __half* xb    = h_buf + (size_t)NN * 256;               // NN*64  (6.4MB)
    __half* w0ph  = xb + (size_t)NN * 64;                   // 32768
    __half* w0pl  = w0ph + 32768;
    __half* w1ph  = w0pl + 32768;                           // 16384
    __half* w1pl  = w1ph + 16384;
    __half* w2ph  = w1pl + 16384;
    __half* w2pl  = w2ph + 16384;
    float*  al_s  = (float*)(w2pl + 16384);                 // NN*4
    float*  al_d  = al_s + (size_t)NN * 4;                  // NN*4
    int*    deg   = (int*)(al_d + (size_t)NN * 4);          // NN
    unsigned short* csr = (unsigned short*)(deg + NN);      // NN*CAP (6.4MB)

    hipMemsetAsync(deg, 0, NN * sizeof(int), stream);
    build_csr_w<<<EBLK + 32, 256, 0, stream>>>(ei, deg, csr, W0, W1, W2,
                                               w0ph, w0pl, w1ph, w1pl, w2ph, w2pl);

    const int gemm_grid = (NN + 63) / 64;
    const int agg_grid  = (NN + 3) / 4;

    // layer 0 (fp32 x, Markidis 3-mul)
    gemm_mfma<FIN, true><<<gemm_grid, 256, 0, stream>>>(x, w0ph, w0pl, as0, ad0, h_buf, al_s, al_d);
    gat_aggregate<<<agg_grid, 256, 0, stream>>>(h_buf, al_s, al_d, deg, csr, b0, xb);
    // layer 1 (fp16 x, 2-mul)
    gemm_mfma<CC, false><<<gemm_grid, 256, 0, stream>>>(xb, w1ph, w1pl, as1, ad1, h_buf, al_s, al_d);
    gat_aggregate<<<agg_grid, 256, 0, stream>>>(h_buf, al_s, al_d, deg, csr, b1, xb);
    // layer 2
    gemm_mfma<CC, false><<<gemm_grid, 256, 0, stream>>>(xb, w2ph, w2pl, as2, ad2, h_buf, al_s, al_d);
    gat_aggregate<<<agg_grid, 256, 0, stream>>>(h_buf, al_s, al_d, deg, csr, b2, xb);

    // fused readout + MLP
    readout_mlp<<<GG, 256, 0, stream>>>(xb, batch, Wr1, br1, Wr2, br2, out);
}